// Round 8
// baseline (87.054 us; speedup 1.0000x reference)
//
#include <hip/hip_runtime.h>

typedef __bf16 bf16x8 __attribute__((ext_vector_type(8)));
typedef float f32x4 __attribute__((ext_vector_type(4)));
typedef unsigned short u16;
typedef unsigned int u32;
typedef unsigned long long u64;

__device__ __forceinline__ float bf2f(u16 x){ u32 u = ((u32)x)<<16; return __builtin_bit_cast(float,u); }
__device__ __forceinline__ u16 f2bf(float f){ u32 u = __builtin_bit_cast(u32,f); u = (u + 0x7fffu + ((u>>16)&1u)) >> 16; return (u16)u; }

__device__ __forceinline__ void glds16(const u16* g, u16* l){
  __builtin_amdgcn_global_load_lds((const __attribute__((address_space(1))) u32*)g,
                                   (__attribute__((address_space(3))) u32*)l, 16, 0, 0);
}

static constexpr float L2E = 1.4426950408889634f;
static constexpr float QSC = 0.125f * 1.4426950408889634f;  // SCALE * log2(e)

// --- merged f32->bf16 converts (x, w_qkv, w_proj) + packed rel table -------
// relT2[h][i] = u64 of 4 bf16 {rel[i-3],rel[i-2],rel[i-1],rel[i]} * log2(e)
__global__ void k_cvtall(const float* __restrict__ x, const float* __restrict__ wq,
                         const float* __restrict__ wp, const float* __restrict__ rt,
                         u16* __restrict__ xo, u16* __restrict__ wqo,
                         u16* __restrict__ wpo, u64* __restrict__ rel2){
  int bid = blockIdx.x;
  if (bid < 5120){
    int i = bid*256 + threadIdx.x;       // float4 index over 1310720 total
    const float* s; u16* d; int base;
    if (i < 1048576){ s=x; d=xo; base=0; }
    else if (i < 1245184){ s=wq; d=wqo; base=1048576; }
    else { s=wp; d=wpo; base=1245184; }
    int j = i - base;
    float4 v = reinterpret_cast<const float4*>(s)[j];
    reinterpret_cast<ushort4*>(d)[j] = make_ushort4(f2bf(v.x),f2bf(v.y),f2bf(v.z),f2bf(v.w));
  } else {
    int i = (bid-5120)*256 + threadIdx.x;
    if (i < 31752){
      int h = i / 3969, i2 = i - h*3969;
      u64 v = 0;
      #pragma unroll
      for (int j=0;j<4;j++){
        int idx = i2-3+j;
        u16 bb = 0;
        if (idx >= 0) bb = f2bf(rt[idx*8+h]*L2E);
        v |= (u64)bb << (16*j);
      }
      rel2[i] = v;
    }
  }
}

__device__ __forceinline__ void acc8(float* acc, uint4 v, float w){
  acc[0]=fmaf(w, bf2f((u16)(v.x)),     acc[0]); acc[1]=fmaf(w, bf2f((u16)(v.x>>16)), acc[1]);
  acc[2]=fmaf(w, bf2f((u16)(v.y)),     acc[2]); acc[3]=fmaf(w, bf2f((u16)(v.y>>16)), acc[3]);
  acc[4]=fmaf(w, bf2f((u16)(v.z)),     acc[4]); acc[5]=fmaf(w, bf2f((u16)(v.z>>16)), acc[5]);
  acc[6]=fmaf(w, bf2f((u16)(v.w)),     acc[6]); acc[7]=fmaf(w, bf2f((u16)(v.w>>16)), acc[7]);
}

// ---------------- 128x128 tile bf16 MFMA GEMM, C = A * Bw^T + bias ---------
// Triple-buffered LDS, single barrier per k-step (stage issued post-barrier),
// counted vmcnt. XCD-aware swizzle. MODE 0: qkv scatter. MODE 1: f32 out.
template<int MODE>
__global__ __launch_bounds__(256) void k_gemm(
  const u16* __restrict__ A, const u16* __restrict__ Bw, const float* __restrict__ bias,
  u16* __restrict__ qo, u16* __restrict__ ko, u16* __restrict__ vo, float* __restrict__ co)
{
  constexpr int K = 512;
  constexpr int NX = (MODE==0) ? 12 : 4;
  constexpr int CPX = NX*64/8;
  __shared__ __align__(16) u16 lA[3][4096];
  __shared__ __align__(16) u16 lB[3][4096];
  const int lin = blockIdx.y*NX + blockIdx.x;
  const int swz = (lin&7)*CPX + (lin>>3);
  const int i0 = (swz/NX)*128, j0 = (swz%NX)*128;
  const int T = threadIdx.x;
  const int w = T>>6, lane = T&63, g = lane>>4, cl = lane&15;
  const int wr = (w>>1)*64, wc = (w&1)*64;
  const int sr = T>>2, sk = 8*(T&3);
  f32x4 acc[4][4];
  #pragma unroll
  for (int a=0;a<4;a++)
    #pragma unroll
    for (int b=0;b<4;b++) acc[a][b] = (f32x4){0.f,0.f,0.f,0.f};

  auto STAGE = [&](int t, u16* bA, u16* bB){
    glds16(A  + (long)(i0+sr)*K    + t*32 + sk, bA + 8*T);
    glds16(A  + (long)(i0+64+sr)*K + t*32 + sk, bA + 2048 + 8*T);
    glds16(Bw + (long)(j0+sr)*K    + t*32 + sk, bB + 8*T);
    glds16(Bw + (long)(j0+64+sr)*K + t*32 + sk, bB + 2048 + 8*T);
  };
  STAGE(0, lA[0], lB[0]);
  STAGE(1, lA[1], lB[1]);
  int cur = 0, sb = 2;
  for (int t=0;t<16;t++){
    if (t<15) asm volatile("s_waitcnt vmcnt(4)" ::: "memory");
    else      asm volatile("s_waitcnt vmcnt(0)" ::: "memory");
    __builtin_amdgcn_s_barrier();
    asm volatile("" ::: "memory");
    if (t<14) STAGE(t+2, lA[sb], lB[sb]);
    const u16* cA = lA[cur];
    const u16* cB = lB[cur];
    bf16x8 af[4], bfr[4];
    #pragma unroll
    for (int mf=0;mf<4;mf++) af[mf]  = *reinterpret_cast<const bf16x8*>(cA + (wr+16*mf+cl)*32 + 8*g);
    #pragma unroll
    for (int nf=0;nf<4;nf++) bfr[nf] = *reinterpret_cast<const bf16x8*>(cB + (wc+16*nf+cl)*32 + 8*g);
    __builtin_amdgcn_s_setprio(1);
    #pragma unroll
    for (int mf=0;mf<4;mf++)
      #pragma unroll
      for (int nf=0;nf<4;nf++)
        acc[mf][nf] = __builtin_amdgcn_mfma_f32_16x16x32_bf16(af[mf], bfr[nf], acc[mf][nf], 0,0,0);
    __builtin_amdgcn_s_setprio(0);
    cur = (cur==2)?0:cur+1;
    sb  = (sb==2)?0:sb+1;
  }

  #pragma unroll
  for (int mf=0;mf<4;mf++){
    #pragma unroll
    for (int nf=0;nf<4;nf++){
      const int col = j0 + wc + 16*nf + cl;
      const float bb = bias[col];
      const int row0 = i0 + wr + 16*mf + 4*g;
      if (MODE==0){
        const int part = col>>9, h=(col>>6)&7, dd=col&63;
        const int b = row0>>10, n0 = row0&1023, bh = b*8+h;
        if (part==2){
          // V^T sigma-permuted within 32-token blocks
          const int a32 = n0 & ~31, G = (n0>>2)&7;
          const int stb = ((G&3)<<3) | ((G>>2)<<2);
          ushort4 pk = make_ushort4(f2bf(acc[mf][nf][0]+bb), f2bf(acc[mf][nf][1]+bb),
                                    f2bf(acc[mf][nf][2]+bb), f2bf(acc[mf][nf][3]+bb));
          *reinterpret_cast<ushort4*>(vo + ((long)bh*64+dd)*1024 + a32 + stb) = pk;
        } else {
          #pragma unroll
          for (int e=0;e<4;e++){
            float v = acc[mf][nf][e] + bb;
            if (part==0) qo[((long)bh*1024+n0+e)*64+dd] = f2bf(v*QSC);
            else         ko[((long)bh*1024+n0+e)*64+dd] = f2bf(v);
          }
        }
      } else {
        #pragma unroll
        for (int e=0;e<4;e++)
          co[(long)(row0+e)*512 + col] = acc[mf][nf][e] + bb;
      }
    }
  }
}

// ---------------- fused window attention, v8 -------------------------------
// Conv-on-Q fused into fragment load (qconv kernel deleted; block Q region is
// L1-resident). Quad-buffered K/V LDS, one barrier/tile, counted vmcnt,
// packed-u64 rel gathers with 1-op extraction, 32 q-rows/wave, no-max softmax.
__global__ __launch_bounds__(256,2) void k_attn(
  const u16* __restrict__ Qb, const u16* __restrict__ Kb, const u16* __restrict__ VT,
  const u64* __restrict__ relT2, const float* __restrict__ pw, u16* __restrict__ Ao)
{
  __shared__ __align__(16) u16 kls[4][4096];
  __shared__ __align__(16) u16 vls[4][4096];
  const int bid = blockIdx.x;
  const int xcd = bid&7, slot = bid>>3;
  const int bh = xcd*8 + (slot>>3), rb = slot&7;  // all 8 rowblocks of a bh on one XCD
  const int b = bh>>3, h = bh&7;
  const int T = threadIdx.x, w=T>>6, lane=T&63, g=lane>>4, cl=lane&15;
  const int rowbase = rb*128 + w*32;
  const int qr[2] = { rowbase + cl, rowbase + 16 + cl };
  const u16* Kbh = Kb + (long)bh*65536;
  const u16* Vbh = VT + (long)bh*65536;

  auto STAGE = [&](int m0, int bi){
    #pragma unroll
    for (int s=0;s<2;s++){
      int idx = s*256 + T, row = idx>>3, u = idx&7, sw = (u ^ (row&7))<<3;
      glds16(Kbh + (m0+row)*64 + sw,         kls[bi] + idx*8);
      glds16(Vbh + (long)row*1024 + m0 + sw, vls[bi] + idx*8);
    }
  };
  STAGE(0,0); STAGE(64,1); STAGE(128,2);

  // ---- fused 15-tap conv: build Q' fragments directly (L1-resident) ----
  float wgt[15];
  #pragma unroll
  for (int t=0;t<15;t++) wgt[t] = pw[h*15+t];
  const u16* Qbh = Qb + (long)bh*65536;
  bf16x8 qf[2][2];
  #pragma unroll
  for (int G=0;G<2;G++){
    const int r = qr[G];
    #pragma unroll
    for (int s=0;s<2;s++){
      const int off = 32*s + 8*g;
      float a[8];
      {
        uint4 cv = *reinterpret_cast<const uint4*>(Qbh + r*64 + off);
        a[0]=bf2f((u16)cv.x); a[1]=bf2f((u16)(cv.x>>16));
        a[2]=bf2f((u16)cv.y); a[3]=bf2f((u16)(cv.y>>16));
        a[4]=bf2f((u16)cv.z); a[5]=bf2f((u16)(cv.z>>16));
        a[6]=bf2f((u16)cv.w); a[7]=bf2f((u16)(cv.w>>16));
      }
      #pragma unroll
      for (int t=0;t<15;t++){
        int nn = r - 7 + t;
        if (nn >= 0 && nn < 1024){
          uint4 v = *reinterpret_cast<const uint4*>(Qbh + nn*64 + off);
          acc8(a, v, wgt[t]);
        }
      }
      bf16x8 qq;
      #pragma unroll
      for (int j=0;j<8;j++) qq[j] = (__bf16)a[j];
      qf[G][s] = qq;
    }
  }

  const int rt[2] = { (qr[0]>>5)*63 + (qr[0]&31) + 1984,
                      (qr[1]>>5)*63 + (qr[1]&31) + 1984 };
  const u64* relTh = relT2 + h*3969;
  float lsum[2] = {0.f, 0.f};
  f32x4 oacc[2][4];
  #pragma unroll
  for (int G=0;G<2;G++)
    #pragma unroll
    for (int c=0;c<4;c++) oacc[G][c] = (f32x4){0.f,0.f,0.f,0.f};

  for (int t=0;t<16;t++){
    const int m0 = t<<6;
    // packed rel gathers: one u64 per (G,c) covers e=0..3
    u64 rx[2][4];
    #pragma unroll
    for (int G=0;G<2;G++)
      #pragma unroll
      for (int c=0;c<4;c++){
        const int kk = m0 + 16*c + 4*g;
        rx[G][c] = relTh[rt[G] - ((kk>>5)*63 + (kk&31))];
      }
    if (t<=13)      asm volatile("s_waitcnt vmcnt(16)" ::: "memory");
    else if (t==14) asm volatile("s_waitcnt vmcnt(12)" ::: "memory");
    else            asm volatile("s_waitcnt vmcnt(8)"  ::: "memory");
    __builtin_amdgcn_s_barrier();
    asm volatile("" ::: "memory");
    if (t<13) STAGE(m0+192, (t+3)&3);

    const char* kb = (const char*)kls[t&3];
    const char* vb = (const char*)vls[t&3];
    f32x4 sacc[2][4];
    #pragma unroll
    for (int G=0;G<2;G++)
      #pragma unroll
      for (int c=0;c<4;c++) sacc[G][c] = (f32x4){0.f,0.f,0.f,0.f};
    __builtin_amdgcn_s_setprio(1);
    #pragma unroll
    for (int c=0;c<4;c++){
      const int r = 16*c + cl, rs = r&7;
      const char* kr = kb + r*128;
      bf16x8 kf0 = *reinterpret_cast<const bf16x8*>(kr + ((g    ^rs)<<4));
      bf16x8 kf1 = *reinterpret_cast<const bf16x8*>(kr + (((4+g)^rs)<<4));
      #pragma unroll
      for (int G=0;G<2;G++){
        sacc[G][c] = __builtin_amdgcn_mfma_f32_16x16x32_bf16(kf0, qf[G][0], sacc[G][c],0,0,0);
        sacc[G][c] = __builtin_amdgcn_mfma_f32_16x16x32_bf16(kf1, qf[G][1], sacc[G][c],0,0,0);
      }
    }
    __builtin_amdgcn_s_setprio(0);
    // p = exp2(s + bias); bias extraction 1 op per element
    float p[2][4][4];
    #pragma unroll
    for (int G=0;G<2;G++)
      #pragma unroll
      for (int c=0;c<4;c++){
        const u32 lo = (u32)rx[G][c], hi = (u32)(rx[G][c]>>32);
        const float b0 = __builtin_bit_cast(float, hi & 0xffff0000u);
        const float b1 = __builtin_bit_cast(float, hi << 16);
        const float b2 = __builtin_bit_cast(float, lo & 0xffff0000u);
        const float b3 = __builtin_bit_cast(float, lo << 16);
        p[G][c][0] = __builtin_amdgcn_exp2f(sacc[G][c][0] + b0);
        p[G][c][1] = __builtin_amdgcn_exp2f(sacc[G][c][1] + b1);
        p[G][c][2] = __builtin_amdgcn_exp2f(sacc[G][c][2] + b2);
        p[G][c][3] = __builtin_amdgcn_exp2f(sacc[G][c][3] + b3);
      }
    #pragma unroll
    for (int G=0;G<2;G++)
      #pragma unroll
      for (int c=0;c<4;c++) lsum[G] += (p[G][c][0]+p[G][c][1]) + (p[G][c][2]+p[G][c][3]);
    bf16x8 pa[2][2];
    #pragma unroll
    for (int G=0;G<2;G++)
      #pragma unroll
      for (int e=0;e<4;e++){
        pa[G][0][e]   = (__bf16)p[G][0][e];  pa[G][0][4+e] = (__bf16)p[G][1][e];
        pa[G][1][e]   = (__bf16)p[G][2][e];  pa[G][1][4+e] = (__bf16)p[G][3][e];
      }
    __builtin_amdgcn_s_setprio(1);
    #pragma unroll
    for (int ks=0;ks<2;ks++)
      #pragma unroll
      for (int c2=0;c2<4;c2++){
        const int dd = 16*c2 + cl, dsw = dd&7;
        bf16x8 vf = *reinterpret_cast<const bf16x8*>(vb + dd*128 + (((4*ks+g)^dsw)<<4));
        #pragma unroll
        for (int G=0;G<2;G++)
          oacc[G][c2] = __builtin_amdgcn_mfma_f32_16x16x32_bf16(pa[G][ks], vf, oacc[G][c2],0,0,0);
      }
    __builtin_amdgcn_s_setprio(0);
  }
  #pragma unroll
  for (int G=0;G<2;G++){
    lsum[G] += __shfl_xor(lsum[G], 16, 64);
    lsum[G] += __shfl_xor(lsum[G], 32, 64);
  }
  #pragma unroll
  for (int G=0;G<2;G++)
    #pragma unroll
    for (int e=0;e<4;e++){
      float inv = 1.0f/__shfl(lsum[G], 4*g+e, 64);
      const long orow = (long)b*1024 + rowbase + 16*G + 4*g + e;
      #pragma unroll
      for (int c2=0;c2<4;c2++)
        Ao[orow*512 + h*64 + 16*c2 + cl] = f2bf(oacc[G][c2][e]*inv);
    }
}

extern "C" void kernel_launch(void* const* d_in, const int* in_sizes, int n_in,
                              void* d_out, int out_size, void* d_ws, size_t ws_size,
                              hipStream_t stream)
{
  const float* x         = (const float*)d_in[0];
  const float* w_qkv     = (const float*)d_in[1];
  const float* b_qkv     = (const float*)d_in[2];
  const float* w_proj    = (const float*)d_in[3];
  const float* b_proj    = (const float*)d_in[4];
  const float* rel_table = (const float*)d_in[5];
  const float* pe_w      = (const float*)d_in[6];
  (void)in_sizes; (void)n_in; (void)out_size; (void)ws_size;

  u16* ws    = (u16*)d_ws;
  u16* x_bf  = ws;                  // 8192*512
  u16* wq_bf = x_bf  + 4194304;     // 1536*512
  u16* wp_bf = wq_bf + 786432;      // 512*512
  u16* q_bf  = wp_bf + 262144;      // [B,H,N,64] pre-scaled by 0.125*log2e
  u16* k_bf  = q_bf  + 4194304;     // [B,H,N,64]
  u16* vt_bf = k_bf  + 4194304;     // [B,H,64,N] sigma-permuted tokens
  u16* ao_bf = vt_bf + 4194304;     // attention out [B,N,C]
  u64* relT2 = (u64*)(ao_bf + 4194304);  // [H][3969] packed u64 (8B aligned)

  k_cvtall<<<5245,256,0,stream>>>(x, w_qkv, w_proj, rel_table, x_bf, wq_bf, wp_bf, relT2);
  k_gemm<0><<<dim3(12,64),256,0,stream>>>(x_bf, wq_bf, b_qkv, q_bf, k_bf, vt_bf, nullptr);
  k_attn<<<512,256,0,stream>>>(q_bf, k_bf, vt_bf, relT2, pe_w, ao_bf);
  k_gemm<1><<<dim3(4,64),256,0,stream>>>(ao_bf, wp_bf, b_proj, nullptr, nullptr, nullptr, (float*)d_out);
}

// Round 9
// 82.570 us; speedup vs baseline: 1.0543x; 1.0543x over previous
//
#include <hip/hip_runtime.h>

typedef __bf16 bf16x8 __attribute__((ext_vector_type(8)));
typedef float f32x4 __attribute__((ext_vector_type(4)));
typedef unsigned short u16;
typedef unsigned int u32;
typedef unsigned long long u64;

__device__ __forceinline__ float bf2f(u16 x){ u32 u = ((u32)x)<<16; return __builtin_bit_cast(float,u); }
__device__ __forceinline__ u16 f2bf(float f){ u32 u = __builtin_bit_cast(u32,f); u = (u + 0x7fffu + ((u>>16)&1u)) >> 16; return (u16)u; }

__device__ __forceinline__ void glds16(const u16* g, u16* l){
  __builtin_amdgcn_global_load_lds((const __attribute__((address_space(1))) u32*)g,
                                   (__attribute__((address_space(3))) u32*)l, 16, 0, 0);
}

static constexpr float L2E = 1.4426950408889634f;
static constexpr float QSC = 0.125f * 1.4426950408889634f;  // SCALE * log2(e)

// --- merged f32->bf16 converts (x, w_qkv, w_proj) + packed rel table -------
// relT2[h][i] = u64 of 4 bf16 {rel[i-3],rel[i-2],rel[i-1],rel[i]} * log2(e)
__global__ void k_cvtall(const float* __restrict__ x, const float* __restrict__ wq,
                         const float* __restrict__ wp, const float* __restrict__ rt,
                         u16* __restrict__ xo, u16* __restrict__ wqo,
                         u16* __restrict__ wpo, u64* __restrict__ rel2){
  int bid = blockIdx.x;
  if (bid < 5120){
    int i = bid*256 + threadIdx.x;       // float4 index over 1310720 total
    const float* s; u16* d; int base;
    if (i < 1048576){ s=x; d=xo; base=0; }
    else if (i < 1245184){ s=wq; d=wqo; base=1048576; }
    else { s=wp; d=wpo; base=1245184; }
    int j = i - base;
    float4 v = reinterpret_cast<const float4*>(s)[j];
    reinterpret_cast<ushort4*>(d)[j] = make_ushort4(f2bf(v.x),f2bf(v.y),f2bf(v.z),f2bf(v.w));
  } else {
    int i = (bid-5120)*256 + threadIdx.x;
    if (i < 31752){
      int h = i / 3969, i2 = i - h*3969;
      u64 v = 0;
      #pragma unroll
      for (int j=0;j<4;j++){
        int idx = i2-3+j;
        u16 bb = 0;
        if (idx >= 0) bb = f2bf(rt[idx*8+h]*L2E);
        v |= (u64)bb << (16*j);
      }
      rel2[i] = v;
    }
  }
}

// ------- depthwise 15-tap conv along token axis on pre-scaled Q ------------
__device__ __forceinline__ void acc8(float* acc, uint4 v, float w){
  acc[0]=fmaf(w, bf2f((u16)(v.x)),     acc[0]); acc[1]=fmaf(w, bf2f((u16)(v.x>>16)), acc[1]);
  acc[2]=fmaf(w, bf2f((u16)(v.y)),     acc[2]); acc[3]=fmaf(w, bf2f((u16)(v.y>>16)), acc[3]);
  acc[4]=fmaf(w, bf2f((u16)(v.z)),     acc[4]); acc[5]=fmaf(w, bf2f((u16)(v.z>>16)), acc[5]);
  acc[6]=fmaf(w, bf2f((u16)(v.w)),     acc[6]); acc[7]=fmaf(w, bf2f((u16)(v.w>>16)), acc[7]);
}
__global__ void k_qconv(const u16* __restrict__ q, u16* __restrict__ qp, const float* __restrict__ pw){
  int idx = blockIdx.x*256 + threadIdx.x;      // 524288 = 64bh * 1024n * 8 dchunks
  int dc = idx&7, n = (idx>>3)&1023, bh = idx>>13, h = bh&7;
  const u16* base = q + (long)bh*65536 + dc*8;
  float wgt[15];
  #pragma unroll
  for (int t=0;t<15;t++) wgt[t] = pw[h*15+t];
  float acc[8];
  {
    uint4 cv = *reinterpret_cast<const uint4*>(base + n*64);
    acc[0]=bf2f((u16)cv.x); acc[1]=bf2f((u16)(cv.x>>16));
    acc[2]=bf2f((u16)cv.y); acc[3]=bf2f((u16)(cv.y>>16));
    acc[4]=bf2f((u16)cv.z); acc[5]=bf2f((u16)(cv.z>>16));
    acc[6]=bf2f((u16)cv.w); acc[7]=bf2f((u16)(cv.w>>16));
  }
  #pragma unroll
  for (int t=0;t<15;t++){
    int nn = n - 7 + t;
    if (nn >= 0 && nn < 1024){
      uint4 v = *reinterpret_cast<const uint4*>(base + nn*64);
      acc8(acc, v, wgt[t]);
    }
  }
  u16* out = qp + (long)bh*65536 + n*64 + dc*8;
  *reinterpret_cast<ushort4*>(out)   = make_ushort4(f2bf(acc[0]),f2bf(acc[1]),f2bf(acc[2]),f2bf(acc[3]));
  *reinterpret_cast<ushort4*>(out+4) = make_ushort4(f2bf(acc[4]),f2bf(acc[5]),f2bf(acc[6]),f2bf(acc[7]));
}

// ---------------- bf16 MFMA GEMM, C = A * Bw^T + bias ----------------------
// MODE 0: 128x128 tile, qkv scatter. MODE 1: 64x128 tile (2 blocks/CU), f32.
// Triple-buffered LDS, single barrier/k-step, counted vmcnt, XCD swizzle.
template<int MODE>
__global__ __launch_bounds__(256) void k_gemm(
  const u16* __restrict__ A, const u16* __restrict__ Bw, const float* __restrict__ bias,
  u16* __restrict__ qo, u16* __restrict__ ko, u16* __restrict__ vo, float* __restrict__ co)
{
  constexpr int K = 512;
  constexpr int BM = (MODE==0) ? 128 : 64;
  constexpr int NX = (MODE==0) ? 12 : 4;
  constexpr int CPX = NX*(8192/BM)/8;
  constexpr int NF = (MODE==0) ? 4 : 2;
  __shared__ __align__(16) u16 lA[3][BM*32];
  __shared__ __align__(16) u16 lB[3][4096];
  const int lin = blockIdx.y*NX + blockIdx.x;
  const int swz = (lin&7)*CPX + (lin>>3);
  const int i0 = (swz/NX)*BM, j0 = (swz%NX)*128;
  const int T = threadIdx.x;
  const int w = T>>6, lane = T&63, g = lane>>4, cl = lane&15;
  const int wr = (MODE==0) ? (w>>1)*64 : 0;
  const int wc = (MODE==0) ? (w&1)*64 : w*32;
  const int sr = T>>2, sk = 8*(T&3);
  f32x4 acc[4][NF];
  #pragma unroll
  for (int a=0;a<4;a++)
    #pragma unroll
    for (int b=0;b<NF;b++) acc[a][b] = (f32x4){0.f,0.f,0.f,0.f};

  auto STAGE = [&](int t, u16* bA, u16* bB){
    glds16(A  + (long)(i0+sr)*K    + t*32 + sk, bA + 8*T);
    if (MODE==0) glds16(A + (long)(i0+64+sr)*K + t*32 + sk, bA + 2048 + 8*T);
    glds16(Bw + (long)(j0+sr)*K    + t*32 + sk, bB + 8*T);
    glds16(Bw + (long)(j0+64+sr)*K + t*32 + sk, bB + 2048 + 8*T);
  };
  STAGE(0, lA[0], lB[0]);
  STAGE(1, lA[1], lB[1]);
  int cur = 0, sb = 2;
  for (int t=0;t<16;t++){
    if (t<15){
      if (MODE==0) asm volatile("s_waitcnt vmcnt(4)" ::: "memory");
      else         asm volatile("s_waitcnt vmcnt(3)" ::: "memory");
    } else {
      asm volatile("s_waitcnt vmcnt(0)" ::: "memory");
    }
    __builtin_amdgcn_s_barrier();
    asm volatile("" ::: "memory");
    if (t<14) STAGE(t+2, lA[sb], lB[sb]);
    const u16* cA = lA[cur];
    const u16* cB = lB[cur];
    bf16x8 af[4], bfr[NF];
    #pragma unroll
    for (int mf=0;mf<4;mf++) af[mf]  = *reinterpret_cast<const bf16x8*>(cA + (wr+16*mf+cl)*32 + 8*g);
    #pragma unroll
    for (int nf=0;nf<NF;nf++) bfr[nf] = *reinterpret_cast<const bf16x8*>(cB + (wc+16*nf+cl)*32 + 8*g);
    __builtin_amdgcn_s_setprio(1);
    #pragma unroll
    for (int mf=0;mf<4;mf++)
      #pragma unroll
      for (int nf=0;nf<NF;nf++)
        acc[mf][nf] = __builtin_amdgcn_mfma_f32_16x16x32_bf16(af[mf], bfr[nf], acc[mf][nf], 0,0,0);
    __builtin_amdgcn_s_setprio(0);
    cur = (cur==2)?0:cur+1;
    sb  = (sb==2)?0:sb+1;
  }

  #pragma unroll
  for (int mf=0;mf<4;mf++){
    #pragma unroll
    for (int nf=0;nf<NF;nf++){
      const int col = j0 + wc + 16*nf + cl;
      const float bb = bias[col];
      const int row0 = i0 + wr + 16*mf + 4*g;
      if (MODE==0){
        const int part = col>>9, h=(col>>6)&7, dd=col&63;
        const int b = row0>>10, n0 = row0&1023, bh = b*8+h;
        if (part==2){
          // V^T sigma-permuted within 32-token blocks
          const int a32 = n0 & ~31, G = (n0>>2)&7;
          const int stb = ((G&3)<<3) | ((G>>2)<<2);
          ushort4 pk = make_ushort4(f2bf(acc[mf][nf][0]+bb), f2bf(acc[mf][nf][1]+bb),
                                    f2bf(acc[mf][nf][2]+bb), f2bf(acc[mf][nf][3]+bb));
          *reinterpret_cast<ushort4*>(vo + ((long)bh*64+dd)*1024 + a32 + stb) = pk;
        } else {
          #pragma unroll
          for (int e=0;e<4;e++){
            float v = acc[mf][nf][e] + bb;
            if (part==0) qo[((long)bh*1024+n0+e)*64+dd] = f2bf(v*QSC);
            else         ko[((long)bh*1024+n0+e)*64+dd] = f2bf(v);
          }
        }
      } else {
        #pragma unroll
        for (int e=0;e<4;e++)
          co[(long)(row0+e)*512 + col] = acc[mf][nf][e] + bb;
      }
    }
  }
}

// ---------------- fused window attention, v9 -------------------------------
// T15 two-tile software pipeline: iter t = QK(t) MFMA || softmax+PV(t-1) VALU.
// Static pingpong regs (saccA/B, rxA/B), quad-buffer K/V staged 2-ahead,
// one barrier/tile, constant vmcnt(12), packed-u64 rel, no-max softmax.
__global__ __launch_bounds__(256,2) void k_attn(
  const u16* __restrict__ Qp, const u16* __restrict__ Kb, const u16* __restrict__ VT,
  const u64* __restrict__ relT2, u16* __restrict__ Ao)
{
  __shared__ __align__(16) u16 kls[4][4096];
  __shared__ __align__(16) u16 vls[4][4096];
  const int bid = blockIdx.x;
  const int xcd = bid&7, slot = bid>>3;
  const int bh = xcd*8 + (slot>>3), rb = slot&7;  // all 8 rowblocks of a bh on one XCD
  const int b = bh>>3, h = bh&7;
  const int T = threadIdx.x, w=T>>6, lane=T&63, g=lane>>4, cl=lane&15;
  const int rowbase = rb*128 + w*32;
  const int qr0 = rowbase + cl, qr1 = rowbase + 16 + cl;
  bf16x8 qf[2][2];
  {
    const u16* Qr0 = Qp + ((long)bh*1024 + qr0)*64;
    const u16* Qr1 = Qp + ((long)bh*1024 + qr1)*64;
    qf[0][0] = *reinterpret_cast<const bf16x8*>(Qr0 + 8*g);
    qf[0][1] = *reinterpret_cast<const bf16x8*>(Qr0 + 32 + 8*g);
    qf[1][0] = *reinterpret_cast<const bf16x8*>(Qr1 + 8*g);
    qf[1][1] = *reinterpret_cast<const bf16x8*>(Qr1 + 32 + 8*g);
  }
  const int rt[2] = { (qr0>>5)*63 + (qr0&31) + 1984,
                      (qr1>>5)*63 + (qr1&31) + 1984 };
  const u64* relTh = relT2 + h*3969;
  const u16* Kbh = Kb + (long)bh*65536;
  const u16* Vbh = VT + (long)bh*65536;
  float lsum[2] = {0.f, 0.f};
  f32x4 oacc[2][4];
  #pragma unroll
  for (int G=0;G<2;G++)
    #pragma unroll
    for (int c=0;c<4;c++) oacc[G][c] = (f32x4){0.f,0.f,0.f,0.f};

  auto STAGE = [&](int m0, int bi){
    #pragma unroll
    for (int s=0;s<2;s++){
      int idx = s*256 + T, row = idx>>3, u = idx&7, sw = (u ^ (row&7))<<3;
      glds16(Kbh + (m0+row)*64 + sw,         kls[bi] + idx*8);
      glds16(Vbh + (long)row*1024 + m0 + sw, vls[bi] + idx*8);
    }
  };
  auto QK = [&](const char* kb, f32x4 (&sacc)[2][4]){
    #pragma unroll
    for (int G=0;G<2;G++)
      #pragma unroll
      for (int c=0;c<4;c++) sacc[G][c] = (f32x4){0.f,0.f,0.f,0.f};
    __builtin_amdgcn_s_setprio(1);
    #pragma unroll
    for (int c=0;c<4;c++){
      const int r = 16*c + cl, rs = r&7;
      const char* kr = kb + r*128;
      bf16x8 kf0 = *reinterpret_cast<const bf16x8*>(kr + ((g    ^rs)<<4));
      bf16x8 kf1 = *reinterpret_cast<const bf16x8*>(kr + (((4+g)^rs)<<4));
      #pragma unroll
      for (int G=0;G<2;G++){
        sacc[G][c] = __builtin_amdgcn_mfma_f32_16x16x32_bf16(kf0, qf[G][0], sacc[G][c],0,0,0);
        sacc[G][c] = __builtin_amdgcn_mfma_f32_16x16x32_bf16(kf1, qf[G][1], sacc[G][c],0,0,0);
      }
    }
    __builtin_amdgcn_s_setprio(0);
  };
  auto RELLOAD = [&](int t, u64 (&rx)[2][4]){
    #pragma unroll
    for (int G=0;G<2;G++)
      #pragma unroll
      for (int c=0;c<4;c++){
        const int kk = (t<<6) + 16*c + 4*g;
        rx[G][c] = relTh[rt[G] - ((kk>>5)*63 + (kk&31))];
      }
  };
  auto SMPV = [&](const char* vb, f32x4 (&sacc)[2][4], u64 (&rx)[2][4]){
    float p[2][4][4];
    #pragma unroll
    for (int G=0;G<2;G++)
      #pragma unroll
      for (int c=0;c<4;c++){
        const u32 lo = (u32)rx[G][c], hi = (u32)(rx[G][c]>>32);
        const float b0 = __builtin_bit_cast(float, hi & 0xffff0000u);
        const float b1 = __builtin_bit_cast(float, hi << 16);
        const float b2 = __builtin_bit_cast(float, lo & 0xffff0000u);
        const float b3 = __builtin_bit_cast(float, lo << 16);
        p[G][c][0] = __builtin_amdgcn_exp2f(sacc[G][c][0] + b0);
        p[G][c][1] = __builtin_amdgcn_exp2f(sacc[G][c][1] + b1);
        p[G][c][2] = __builtin_amdgcn_exp2f(sacc[G][c][2] + b2);
        p[G][c][3] = __builtin_amdgcn_exp2f(sacc[G][c][3] + b3);
      }
    #pragma unroll
    for (int G=0;G<2;G++)
      #pragma unroll
      for (int c=0;c<4;c++) lsum[G] += (p[G][c][0]+p[G][c][1]) + (p[G][c][2]+p[G][c][3]);
    bf16x8 pa[2][2];
    #pragma unroll
    for (int G=0;G<2;G++)
      #pragma unroll
      for (int e=0;e<4;e++){
        pa[G][0][e]   = (__bf16)p[G][0][e];  pa[G][0][4+e] = (__bf16)p[G][1][e];
        pa[G][1][e]   = (__bf16)p[G][2][e];  pa[G][1][4+e] = (__bf16)p[G][3][e];
      }
    __builtin_amdgcn_s_setprio(1);
    #pragma unroll
    for (int ks=0;ks<2;ks++)
      #pragma unroll
      for (int c2=0;c2<4;c2++){
        const int dd = 16*c2 + cl, dsw = dd&7;
        bf16x8 vf = *reinterpret_cast<const bf16x8*>(vb + dd*128 + (((4*ks+g)^dsw)<<4));
        #pragma unroll
        for (int G=0;G<2;G++)
          oacc[G][c2] = __builtin_amdgcn_mfma_f32_16x16x32_bf16(pa[G][ks], vf, oacc[G][c2],0,0,0);
      }
    __builtin_amdgcn_s_setprio(0);
  };

  f32x4 saccA[2][4], saccB[2][4];
  u64 rxA[2][4], rxB[2][4];

  // prologue: stage tiles 0,1; wait tile 0
  STAGE(0,0); STAGE(64,1);
  asm volatile("s_waitcnt vmcnt(4)" ::: "memory");
  __builtin_amdgcn_s_barrier();
  asm volatile("" ::: "memory");

  for (int tp=0; tp<7; ++tp){
    const int t0 = 2*tp, t1 = t0+1;
    // even tile t0: QK(t0) || softmax+PV(t0-1)
    QK((const char*)kls[t0&3], saccA);
    RELLOAD(t0, rxA);
    if (tp>0) SMPV((const char*)vls[(t0-1)&3], saccB, rxB);
    STAGE((t0+2)<<6, (t0+2)&3);
    asm volatile("s_waitcnt vmcnt(12)" ::: "memory");
    __builtin_amdgcn_s_barrier();
    asm volatile("" ::: "memory");
    // odd tile t1
    QK((const char*)kls[t1&3], saccB);
    RELLOAD(t1, rxB);
    SMPV((const char*)vls[t0&3], saccA, rxA);
    STAGE((t1+2)<<6, (t1+2)&3);
    asm volatile("s_waitcnt vmcnt(12)" ::: "memory");
    __builtin_amdgcn_s_barrier();
    asm volatile("" ::: "memory");
  }
  // t=14 (even): no stage
  QK((const char*)kls[2], saccA);
  RELLOAD(14, rxA);
  SMPV((const char*)vls[1], saccB, rxB);            // tile 13
  asm volatile("s_waitcnt vmcnt(8)" ::: "memory");
  __builtin_amdgcn_s_barrier();
  asm volatile("" ::: "memory");
  // t=15 (odd): no stage, no barrier
  QK((const char*)kls[3], saccB);
  RELLOAD(15, rxB);
  SMPV((const char*)vls[2], saccA, rxA);            // tile 14
  SMPV((const char*)vls[3], saccB, rxB);            // tile 15 (epilogue)

  #pragma unroll
  for (int G=0;G<2;G++){
    lsum[G] += __shfl_xor(lsum[G], 16, 64);
    lsum[G] += __shfl_xor(lsum[G], 32, 64);
  }
  #pragma unroll
  for (int G=0;G<2;G++)
    #pragma unroll
    for (int e=0;e<4;e++){
      float inv = 1.0f/__shfl(lsum[G], 4*g+e, 64);
      const long orow = (long)b*1024 + rowbase + 16*G + 4*g + e;
      #pragma unroll
      for (int c2=0;c2<4;c2++)
        Ao[orow*512 + h*64 + 16*c2 + cl] = f2bf(oacc[G][c2][e]*inv);
    }
}

extern "C" void kernel_launch(void* const* d_in, const int* in_sizes, int n_in,
                              void* d_out, int out_size, void* d_ws, size_t ws_size,
                              hipStream_t stream)
{
  const float* x         = (const float*)d_in[0];
  const float* w_qkv     = (const float*)d_in[1];
  const float* b_qkv     = (const float*)d_in[2];
  const float* w_proj    = (const float*)d_in[3];
  const float* b_proj    = (const float*)d_in[4];
  const float* rel_table = (const float*)d_in[5];
  const float* pe_w      = (const float*)d_in[6];
  (void)in_sizes; (void)n_in; (void)out_size; (void)ws_size;

  u16* ws    = (u16*)d_ws;
  u16* x_bf  = ws;                  // 8192*512
  u16* wq_bf = x_bf  + 4194304;     // 1536*512
  u16* wp_bf = wq_bf + 786432;      // 512*512
  u16* q_bf  = wp_bf + 262144;      // [B,H,N,64] pre-scaled by 0.125*log2e
  u16* k_bf  = q_bf  + 4194304;     // [B,H,N,64]
  u16* vt_bf = k_bf  + 4194304;     // [B,H,64,N] sigma-permuted tokens
  u16* qp_bf = vt_bf + 4194304;     // Q' = q~ + conv(q~)
  u16* ao_bf = qp_bf + 4194304;     // attention out [B,N,C]
  u64* relT2 = (u64*)(ao_bf + 4194304);  // [H][3969] packed u64 (8B aligned)

  k_cvtall<<<5245,256,0,stream>>>(x, w_qkv, w_proj, rel_table, x_bf, wq_bf, wp_bf, relT2);
  k_gemm<0><<<dim3(12,64),256,0,stream>>>(x_bf, wq_bf, b_qkv, q_bf, k_bf, vt_bf, nullptr);
  k_qconv<<<2048,256,0,stream>>>(q_bf, qp_bf, pe_w);
  k_attn<<<512,256,0,stream>>>(qp_bf, k_bf, vt_bf, relT2, ao_bf);
  k_gemm<1><<<dim3(4,128),256,0,stream>>>(ao_bf, wp_bf, b_proj, nullptr, nullptr, nullptr, (float*)d_out);
}

// Round 10
// 82.188 us; speedup vs baseline: 1.0592x; 1.0046x over previous
//
#include <hip/hip_runtime.h>

typedef __bf16 bf16x8 __attribute__((ext_vector_type(8)));
typedef float f32x4 __attribute__((ext_vector_type(4)));
typedef unsigned short u16;
typedef unsigned int u32;
typedef unsigned long long u64;

__device__ __forceinline__ float bf2f(u16 x){ u32 u = ((u32)x)<<16; return __builtin_bit_cast(float,u); }
__device__ __forceinline__ u16 f2bf(float f){ u32 u = __builtin_bit_cast(u32,f); u = (u + 0x7fffu + ((u>>16)&1u)) >> 16; return (u16)u; }

__device__ __forceinline__ void glds16(const u16* g, u16* l){
  __builtin_amdgcn_global_load_lds((const __attribute__((address_space(1))) u32*)g,
                                   (__attribute__((address_space(3))) u32*)l, 16, 0, 0);
}

static constexpr float L2E = 1.4426950408889634f;
static constexpr float QSC = 0.125f * 1.4426950408889634f;  // SCALE * log2(e)

// --- merged f32->bf16 converts (x, w_qkv, w_proj) + packed rel table -------
// relT2[h][i] = u64 of 4 bf16 {rel[i-3],rel[i-2],rel[i-1],rel[i]} * log2(e)
__global__ void k_cvtall(const float* __restrict__ x, const float* __restrict__ wq,
                         const float* __restrict__ wp, const float* __restrict__ rt,
                         u16* __restrict__ xo, u16* __restrict__ wqo,
                         u16* __restrict__ wpo, u64* __restrict__ rel2){
  int bid = blockIdx.x;
  if (bid < 5120){
    int i = bid*256 + threadIdx.x;       // float4 index over 1310720 total
    const float* s; u16* d; int base;
    if (i < 1048576){ s=x; d=xo; base=0; }
    else if (i < 1245184){ s=wq; d=wqo; base=1048576; }
    else { s=wp; d=wpo; base=1245184; }
    int j = i - base;
    float4 v = reinterpret_cast<const float4*>(s)[j];
    reinterpret_cast<ushort4*>(d)[j] = make_ushort4(f2bf(v.x),f2bf(v.y),f2bf(v.z),f2bf(v.w));
  } else {
    int i = (bid-5120)*256 + threadIdx.x;
    if (i < 31752){
      int h = i / 3969, i2 = i - h*3969;
      u64 v = 0;
      #pragma unroll
      for (int j=0;j<4;j++){
        int idx = i2-3+j;
        u16 bb = 0;
        if (idx >= 0) bb = f2bf(rt[idx*8+h]*L2E);
        v |= (u64)bb << (16*j);
      }
      rel2[i] = v;
    }
  }
}

// ------- depthwise 15-tap conv along token axis on pre-scaled Q ------------
__device__ __forceinline__ void acc8(float* acc, uint4 v, float w){
  acc[0]=fmaf(w, bf2f((u16)(v.x)),     acc[0]); acc[1]=fmaf(w, bf2f((u16)(v.x>>16)), acc[1]);
  acc[2]=fmaf(w, bf2f((u16)(v.y)),     acc[2]); acc[3]=fmaf(w, bf2f((u16)(v.y>>16)), acc[3]);
  acc[4]=fmaf(w, bf2f((u16)(v.z)),     acc[4]); acc[5]=fmaf(w, bf2f((u16)(v.z>>16)), acc[5]);
  acc[6]=fmaf(w, bf2f((u16)(v.w)),     acc[6]); acc[7]=fmaf(w, bf2f((u16)(v.w>>16)), acc[7]);
}
__global__ void k_qconv(const u16* __restrict__ q, u16* __restrict__ qp, const float* __restrict__ pw){
  int idx = blockIdx.x*256 + threadIdx.x;      // 524288 = 64bh * 1024n * 8 dchunks
  int dc = idx&7, n = (idx>>3)&1023, bh = idx>>13, h = bh&7;
  const u16* base = q + (long)bh*65536 + dc*8;
  float wgt[15];
  #pragma unroll
  for (int t=0;t<15;t++) wgt[t] = pw[h*15+t];
  float acc[8];
  {
    uint4 cv = *reinterpret_cast<const uint4*>(base + n*64);
    acc[0]=bf2f((u16)cv.x); acc[1]=bf2f((u16)(cv.x>>16));
    acc[2]=bf2f((u16)cv.y); acc[3]=bf2f((u16)(cv.y>>16));
    acc[4]=bf2f((u16)cv.z); acc[5]=bf2f((u16)(cv.z>>16));
    acc[6]=bf2f((u16)cv.w); acc[7]=bf2f((u16)(cv.w>>16));
  }
  #pragma unroll
  for (int t=0;t<15;t++){
    int nn = n - 7 + t;
    if (nn >= 0 && nn < 1024){
      uint4 v = *reinterpret_cast<const uint4*>(base + nn*64);
      acc8(acc, v, wgt[t]);
    }
  }
  u16* out = qp + (long)bh*65536 + n*64 + dc*8;
  *reinterpret_cast<ushort4*>(out)   = make_ushort4(f2bf(acc[0]),f2bf(acc[1]),f2bf(acc[2]),f2bf(acc[3]));
  *reinterpret_cast<ushort4*>(out+4) = make_ushort4(f2bf(acc[4]),f2bf(acc[5]),f2bf(acc[6]),f2bf(acc[7]));
}

// ---------------- bf16 MFMA GEMM, C = A * Bw^T + bias ----------------------
// MODE 0: 128x128 tile, qkv scatter. MODE 1: 64x128 tile (2 blocks/CU), f32.
// Triple-buffered LDS, single barrier/k-step, counted vmcnt, XCD swizzle.
template<int MODE>
__global__ __launch_bounds__(256) void k_gemm(
  const u16* __restrict__ A, const u16* __restrict__ Bw, const float* __restrict__ bias,
  u16* __restrict__ qo, u16* __restrict__ ko, u16* __restrict__ vo, float* __restrict__ co)
{
  constexpr int K = 512;
  constexpr int BM = (MODE==0) ? 128 : 64;
  constexpr int NX = (MODE==0) ? 12 : 4;
  constexpr int CPX = NX*(8192/BM)/8;
  constexpr int NF = (MODE==0) ? 4 : 2;
  __shared__ __align__(16) u16 lA[3][BM*32];
  __shared__ __align__(16) u16 lB[3][4096];
  const int lin = blockIdx.y*NX + blockIdx.x;
  const int swz = (lin&7)*CPX + (lin>>3);
  const int i0 = (swz/NX)*BM, j0 = (swz%NX)*128;
  const int T = threadIdx.x;
  const int w = T>>6, lane = T&63, g = lane>>4, cl = lane&15;
  const int wr = (MODE==0) ? (w>>1)*64 : 0;
  const int wc = (MODE==0) ? (w&1)*64 : w*32;
  const int sr = T>>2, sk = 8*(T&3);
  f32x4 acc[4][NF];
  #pragma unroll
  for (int a=0;a<4;a++)
    #pragma unroll
    for (int b=0;b<NF;b++) acc[a][b] = (f32x4){0.f,0.f,0.f,0.f};

  auto STAGE = [&](int t, u16* bA, u16* bB){
    glds16(A  + (long)(i0+sr)*K    + t*32 + sk, bA + 8*T);
    if (MODE==0) glds16(A + (long)(i0+64+sr)*K + t*32 + sk, bA + 2048 + 8*T);
    glds16(Bw + (long)(j0+sr)*K    + t*32 + sk, bB + 8*T);
    glds16(Bw + (long)(j0+64+sr)*K + t*32 + sk, bB + 2048 + 8*T);
  };
  STAGE(0, lA[0], lB[0]);
  STAGE(1, lA[1], lB[1]);
  int cur = 0, sb = 2;
  for (int t=0;t<16;t++){
    if (t<15){
      if (MODE==0) asm volatile("s_waitcnt vmcnt(4)" ::: "memory");
      else         asm volatile("s_waitcnt vmcnt(3)" ::: "memory");
    } else {
      asm volatile("s_waitcnt vmcnt(0)" ::: "memory");
    }
    __builtin_amdgcn_s_barrier();
    asm volatile("" ::: "memory");
    if (t<14) STAGE(t+2, lA[sb], lB[sb]);
    const u16* cA = lA[cur];
    const u16* cB = lB[cur];
    bf16x8 af[4], bfr[NF];
    #pragma unroll
    for (int mf=0;mf<4;mf++) af[mf]  = *reinterpret_cast<const bf16x8*>(cA + (wr+16*mf+cl)*32 + 8*g);
    #pragma unroll
    for (int nf=0;nf<NF;nf++) bfr[nf] = *reinterpret_cast<const bf16x8*>(cB + (wc+16*nf+cl)*32 + 8*g);
    __builtin_amdgcn_s_setprio(1);
    #pragma unroll
    for (int mf=0;mf<4;mf++)
      #pragma unroll
      for (int nf=0;nf<NF;nf++)
        acc[mf][nf] = __builtin_amdgcn_mfma_f32_16x16x32_bf16(af[mf], bfr[nf], acc[mf][nf], 0,0,0);
    __builtin_amdgcn_s_setprio(0);
    cur = (cur==2)?0:cur+1;
    sb  = (sb==2)?0:sb+1;
  }

  #pragma unroll
  for (int mf=0;mf<4;mf++){
    #pragma unroll
    for (int nf=0;nf<NF;nf++){
      const int col = j0 + wc + 16*nf + cl;
      const float bb = bias[col];
      const int row0 = i0 + wr + 16*mf + 4*g;
      if (MODE==0){
        const int part = col>>9, h=(col>>6)&7, dd=col&63;
        const int b = row0>>10, n0 = row0&1023, bh = b*8+h;
        if (part==2){
          // V^T sigma-permuted within 32-token blocks
          const int a32 = n0 & ~31, G = (n0>>2)&7;
          const int stb = ((G&3)<<3) | ((G>>2)<<2);
          ushort4 pk = make_ushort4(f2bf(acc[mf][nf][0]+bb), f2bf(acc[mf][nf][1]+bb),
                                    f2bf(acc[mf][nf][2]+bb), f2bf(acc[mf][nf][3]+bb));
          *reinterpret_cast<ushort4*>(vo + ((long)bh*64+dd)*1024 + a32 + stb) = pk;
        } else {
          #pragma unroll
          for (int e=0;e<4;e++){
            float v = acc[mf][nf][e] + bb;
            if (part==0) qo[((long)bh*1024+n0+e)*64+dd] = f2bf(v*QSC);
            else         ko[((long)bh*1024+n0+e)*64+dd] = f2bf(v);
          }
        }
      } else {
        #pragma unroll
        for (int e=0;e<4;e++)
          co[(long)(row0+e)*512 + col] = acc[mf][nf][e] + bb;
      }
    }
  }
}

// ---------------- fused window attention, v10 ------------------------------
// Pair-wise tiles: ONE barrier per 2 KV-tiles (8 per block). Quad-buffer K/V,
// stage pair p+1 at pair-p start; within-pair interleave QK(t1) || SMPV(t0).
// Packed-u64 rel, no-max softmax, 32 q-rows/wave.
__global__ __launch_bounds__(256,2) void k_attn(
  const u16* __restrict__ Qp, const u16* __restrict__ Kb, const u16* __restrict__ VT,
  const u64* __restrict__ relT2, u16* __restrict__ Ao)
{
  __shared__ __align__(16) u16 kls[4][4096];
  __shared__ __align__(16) u16 vls[4][4096];
  const int bid = blockIdx.x;
  const int xcd = bid&7, slot = bid>>3;
  const int bh = xcd*8 + (slot>>3), rb = slot&7;  // all 8 rowblocks of a bh on one XCD
  const int b = bh>>3, h = bh&7;
  const int T = threadIdx.x, w=T>>6, lane=T&63, g=lane>>4, cl=lane&15;
  const int rowbase = rb*128 + w*32;
  const int qr0 = rowbase + cl, qr1 = rowbase + 16 + cl;
  bf16x8 qf[2][2];
  {
    const u16* Qr0 = Qp + ((long)bh*1024 + qr0)*64;
    const u16* Qr1 = Qp + ((long)bh*1024 + qr1)*64;
    qf[0][0] = *reinterpret_cast<const bf16x8*>(Qr0 + 8*g);
    qf[0][1] = *reinterpret_cast<const bf16x8*>(Qr0 + 32 + 8*g);
    qf[1][0] = *reinterpret_cast<const bf16x8*>(Qr1 + 8*g);
    qf[1][1] = *reinterpret_cast<const bf16x8*>(Qr1 + 32 + 8*g);
  }
  const int rt[2] = { (qr0>>5)*63 + (qr0&31) + 1984,
                      (qr1>>5)*63 + (qr1&31) + 1984 };
  const u64* relTh = relT2 + h*3969;
  const u16* Kbh = Kb + (long)bh*65536;
  const u16* Vbh = VT + (long)bh*65536;
  float lsum[2] = {0.f, 0.f};
  f32x4 oacc[2][4];
  #pragma unroll
  for (int G=0;G<2;G++)
    #pragma unroll
    for (int c=0;c<4;c++) oacc[G][c] = (f32x4){0.f,0.f,0.f,0.f};

  auto STAGE = [&](int m0, int bi){
    #pragma unroll
    for (int s=0;s<2;s++){
      int idx = s*256 + T, row = idx>>3, u = idx&7, sw = (u ^ (row&7))<<3;
      glds16(Kbh + (m0+row)*64 + sw,         kls[bi] + idx*8);
      glds16(Vbh + (long)row*1024 + m0 + sw, vls[bi] + idx*8);
    }
  };
  auto QK = [&](const char* kb, f32x4 (&sacc)[2][4]){
    #pragma unroll
    for (int G=0;G<2;G++)
      #pragma unroll
      for (int c=0;c<4;c++) sacc[G][c] = (f32x4){0.f,0.f,0.f,0.f};
    #pragma unroll
    for (int c=0;c<4;c++){
      const int r = 16*c + cl, rs = r&7;
      const char* kr = kb + r*128;
      bf16x8 kf0 = *reinterpret_cast<const bf16x8*>(kr + ((g    ^rs)<<4));
      bf16x8 kf1 = *reinterpret_cast<const bf16x8*>(kr + (((4+g)^rs)<<4));
      #pragma unroll
      for (int G=0;G<2;G++){
        sacc[G][c] = __builtin_amdgcn_mfma_f32_16x16x32_bf16(kf0, qf[G][0], sacc[G][c],0,0,0);
        sacc[G][c] = __builtin_amdgcn_mfma_f32_16x16x32_bf16(kf1, qf[G][1], sacc[G][c],0,0,0);
      }
    }
  };
  auto RELLOAD = [&](int t, u64 (&rx)[2][4]){
    #pragma unroll
    for (int G=0;G<2;G++)
      #pragma unroll
      for (int c=0;c<4;c++){
        const int kk = (t<<6) + 16*c + 4*g;
        rx[G][c] = relTh[rt[G] - ((kk>>5)*63 + (kk&31))];
      }
  };
  auto SMPV = [&](const char* vb, f32x4 (&sacc)[2][4], u64 (&rx)[2][4]){
    float p[2][4][4];
    #pragma unroll
    for (int G=0;G<2;G++)
      #pragma unroll
      for (int c=0;c<4;c++){
        const u32 lo = (u32)rx[G][c], hi = (u32)(rx[G][c]>>32);
        const float b0 = __builtin_bit_cast(float, hi & 0xffff0000u);
        const float b1 = __builtin_bit_cast(float, hi << 16);
        const float b2 = __builtin_bit_cast(float, lo & 0xffff0000u);
        const float b3 = __builtin_bit_cast(float, lo << 16);
        p[G][c][0] = __builtin_amdgcn_exp2f(sacc[G][c][0] + b0);
        p[G][c][1] = __builtin_amdgcn_exp2f(sacc[G][c][1] + b1);
        p[G][c][2] = __builtin_amdgcn_exp2f(sacc[G][c][2] + b2);
        p[G][c][3] = __builtin_amdgcn_exp2f(sacc[G][c][3] + b3);
      }
    #pragma unroll
    for (int G=0;G<2;G++)
      #pragma unroll
      for (int c=0;c<4;c++) lsum[G] += (p[G][c][0]+p[G][c][1]) + (p[G][c][2]+p[G][c][3]);
    bf16x8 pa[2][2];
    #pragma unroll
    for (int G=0;G<2;G++)
      #pragma unroll
      for (int e=0;e<4;e++){
        pa[G][0][e]   = (__bf16)p[G][0][e];  pa[G][0][4+e] = (__bf16)p[G][1][e];
        pa[G][1][e]   = (__bf16)p[G][2][e];  pa[G][1][4+e] = (__bf16)p[G][3][e];
      }
    #pragma unroll
    for (int ks=0;ks<2;ks++)
      #pragma unroll
      for (int c2=0;c2<4;c2++){
        const int dd = 16*c2 + cl, dsw = dd&7;
        bf16x8 vf = *reinterpret_cast<const bf16x8*>(vb + dd*128 + (((4*ks+g)^dsw)<<4));
        #pragma unroll
        for (int G=0;G<2;G++)
          oacc[G][c2] = __builtin_amdgcn_mfma_f32_16x16x32_bf16(pa[G][ks], vf, oacc[G][c2],0,0,0);
      }
  };

  f32x4 saccA[2][4], saccB[2][4];
  u64 rxA[2][4], rxB[2][4];

  // prologue: stage pair 0 (tiles 0,1 -> buffers 0,1)
  STAGE(0,0); STAGE(64,1);
  asm volatile("s_waitcnt vmcnt(0)" ::: "memory");
  __builtin_amdgcn_s_barrier();
  asm volatile("" ::: "memory");

  for (int p=0;p<8;p++){
    const int t0 = 2*p, t1 = t0+1;
    // stage pair p+1 into the other buffer half (read-done since barrier p-1)
    if (p<7){ STAGE((t0+2)<<6, (t0+2)&3); STAGE((t1+2)<<6, (t1+2)&3); }
    asm volatile("" ::: "memory");       // keep rel loads after stage glds
    RELLOAD(t0, rxA);
    RELLOAD(t1, rxB);
    __builtin_amdgcn_s_setprio(1);
    QK((const char*)kls[t0&3], saccA);
    QK((const char*)kls[t1&3], saccB);   // independent of SMPV(t0) -> interleave
    SMPV((const char*)vls[t0&3], saccA, rxA);
    SMPV((const char*)vls[t1&3], saccB, rxB);
    __builtin_amdgcn_s_setprio(0);
    if (p<7){
      // outstanding: this pair's 8 glds (rels consumed above) -> drain them
      asm volatile("s_waitcnt vmcnt(0)" ::: "memory");
      __builtin_amdgcn_s_barrier();
      asm volatile("" ::: "memory");
    }
  }

  #pragma unroll
  for (int G=0;G<2;G++){
    lsum[G] += __shfl_xor(lsum[G], 16, 64);
    lsum[G] += __shfl_xor(lsum[G], 32, 64);
  }
  #pragma unroll
  for (int G=0;G<2;G++)
    #pragma unroll
    for (int e=0;e<4;e++){
      float inv = 1.0f/__shfl(lsum[G], 4*g+e, 64);
      const long orow = (long)b*1024 + rowbase + 16*G + 4*g + e;
      #pragma unroll
      for (int c2=0;c2<4;c2++)
        Ao[orow*512 + h*64 + 16*c2 + cl] = f2bf(oacc[G][c2][e]*inv);
    }
}

extern "C" void kernel_launch(void* const* d_in, const int* in_sizes, int n_in,
                              void* d_out, int out_size, void* d_ws, size_t ws_size,
                              hipStream_t stream)
{
  const float* x         = (const float*)d_in[0];
  const float* w_qkv     = (const float*)d_in[1];
  const float* b_qkv     = (const float*)d_in[2];
  const float* w_proj    = (const float*)d_in[3];
  const float* b_proj    = (const float*)d_in[4];
  const float* rel_table = (const float*)d_in[5];
  const float* pe_w      = (const float*)d_in[6];
  (void)in_sizes; (void)n_in; (void)out_size; (void)ws_size;

  u16* ws    = (u16*)d_ws;
  u16* x_bf  = ws;                  // 8192*512
  u16* wq_bf = x_bf  + 4194304;     // 1536*512
  u16* wp_bf = wq_bf + 786432;      // 512*512
  u16* q_bf  = wp_bf + 262144;      // [B,H,N,64] pre-scaled by 0.125*log2e
  u16* k_bf  = q_bf  + 4194304;     // [B,H,N,64]
  u16* vt_bf = k_bf  + 4194304;     // [B,H,64,N] sigma-permuted tokens
  u16* qp_bf = vt_bf + 4194304;     // Q' = q~ + conv(q~)
  u16* ao_bf = qp_bf + 4194304;     // attention out [B,N,C]
  u64* relT2 = (u64*)(ao_bf + 4194304);  // [H][3969] packed u64 (8B aligned)

  k_cvtall<<<5245,256,0,stream>>>(x, w_qkv, w_proj, rel_table, x_bf, wq_bf, wp_bf, relT2);
  k_gemm<0><<<dim3(12,64),256,0,stream>>>(x_bf, wq_bf, b_qkv, q_bf, k_bf, vt_bf, nullptr);
  k_qconv<<<2048,256,0,stream>>>(q_bf, qp_bf, pe_w);
  k_attn<<<512,256,0,stream>>>(qp_bf, k_bf, vt_bf, relT2, ao_bf);
  k_gemm<1><<<dim3(4,128),256,0,stream>>>(ao_bf, wp_bf, b_proj, nullptr, nullptr, nullptr, (float*)d_out);
}

// Round 11
// 78.303 us; speedup vs baseline: 1.1118x; 1.0496x over previous
//
#include <hip/hip_runtime.h>

typedef __bf16 bf16x8 __attribute__((ext_vector_type(8)));
typedef float f32x4 __attribute__((ext_vector_type(4)));
typedef unsigned short u16;
typedef unsigned int u32;
typedef unsigned long long u64;

__device__ __forceinline__ float bf2f(u16 x){ u32 u = ((u32)x)<<16; return __builtin_bit_cast(float,u); }
__device__ __forceinline__ u16 f2bf(float f){ u32 u = __builtin_bit_cast(u32,f); u = (u + 0x7fffu + ((u>>16)&1u)) >> 16; return (u16)u; }

__device__ __forceinline__ void glds16(const u16* g, u16* l){
  __builtin_amdgcn_global_load_lds((const __attribute__((address_space(1))) u32*)g,
                                   (__attribute__((address_space(3))) u32*)l, 16, 0, 0);
}

static constexpr float L2E = 1.4426950408889634f;
static constexpr float QSC = 0.125f * 1.4426950408889634f;  // SCALE * log2(e)

// --- merged f32->bf16 converts (x, w_qkv, w_proj) + packed rel table -------
// relT2[h][i] = u64 of 4 bf16 {rel[i-3],rel[i-2],rel[i-1],rel[i]} * log2(e)
__global__ void k_cvtall(const float* __restrict__ x, const float* __restrict__ wq,
                         const float* __restrict__ wp, const float* __restrict__ rt,
                         u16* __restrict__ xo, u16* __restrict__ wqo,
                         u16* __restrict__ wpo, u64* __restrict__ rel2){
  int bid = blockIdx.x;
  if (bid < 5120){
    int i = bid*256 + threadIdx.x;       // float4 index over 1310720 total
    const float* s; u16* d; int base;
    if (i < 1048576){ s=x; d=xo; base=0; }
    else if (i < 1245184){ s=wq; d=wqo; base=1048576; }
    else { s=wp; d=wpo; base=1245184; }
    int j = i - base;
    float4 v = reinterpret_cast<const float4*>(s)[j];
    reinterpret_cast<ushort4*>(d)[j] = make_ushort4(f2bf(v.x),f2bf(v.y),f2bf(v.z),f2bf(v.w));
  } else {
    int i = (bid-5120)*256 + threadIdx.x;
    if (i < 31752){
      int h = i / 3969, i2 = i - h*3969;
      u64 v = 0;
      #pragma unroll
      for (int j=0;j<4;j++){
        int idx = i2-3+j;
        u16 bb = 0;
        if (idx >= 0) bb = f2bf(rt[idx*8+h]*L2E);
        v |= (u64)bb << (16*j);
      }
      rel2[i] = v;
    }
  }
}

__device__ __forceinline__ void acc8(float* acc, uint4 v, float w){
  acc[0]=fmaf(w, bf2f((u16)(v.x)),     acc[0]); acc[1]=fmaf(w, bf2f((u16)(v.x>>16)), acc[1]);
  acc[2]=fmaf(w, bf2f((u16)(v.y)),     acc[2]); acc[3]=fmaf(w, bf2f((u16)(v.y>>16)), acc[3]);
  acc[4]=fmaf(w, bf2f((u16)(v.z)),     acc[4]); acc[5]=fmaf(w, bf2f((u16)(v.z>>16)), acc[5]);
  acc[6]=fmaf(w, bf2f((u16)(v.w)),     acc[6]); acc[7]=fmaf(w, bf2f((u16)(v.w>>16)), acc[7]);
}

// ---------------- bf16 MFMA GEMM, C = A * Bw^T + bias ----------------------
// MODE 0: 128x128 tile, qkv scatter. MODE 1: 64x128 tile (2 blocks/CU), f32.
// Triple-buffered LDS, single barrier/k-step, counted vmcnt, XCD swizzle.
template<int MODE>
__global__ __launch_bounds__(256) void k_gemm(
  const u16* __restrict__ A, const u16* __restrict__ Bw, const float* __restrict__ bias,
  u16* __restrict__ qo, u16* __restrict__ ko, u16* __restrict__ vo, float* __restrict__ co)
{
  constexpr int K = 512;
  constexpr int BM = (MODE==0) ? 128 : 64;
  constexpr int NX = (MODE==0) ? 12 : 4;
  constexpr int CPX = NX*(8192/BM)/8;
  constexpr int NF = (MODE==0) ? 4 : 2;
  __shared__ __align__(16) u16 lA[3][BM*32];
  __shared__ __align__(16) u16 lB[3][4096];
  const int lin = blockIdx.y*NX + blockIdx.x;
  const int swz = (lin&7)*CPX + (lin>>3);
  const int i0 = (swz/NX)*BM, j0 = (swz%NX)*128;
  const int T = threadIdx.x;
  const int w = T>>6, lane = T&63, g = lane>>4, cl = lane&15;
  const int wr = (MODE==0) ? (w>>1)*64 : 0;
  const int wc = (MODE==0) ? (w&1)*64 : w*32;
  const int sr = T>>2, sk = 8*(T&3);
  f32x4 acc[4][NF];
  #pragma unroll
  for (int a=0;a<4;a++)
    #pragma unroll
    for (int b=0;b<NF;b++) acc[a][b] = (f32x4){0.f,0.f,0.f,0.f};

  auto STAGE = [&](int t, u16* bA, u16* bB){
    glds16(A  + (long)(i0+sr)*K    + t*32 + sk, bA + 8*T);
    if (MODE==0) glds16(A + (long)(i0+64+sr)*K + t*32 + sk, bA + 2048 + 8*T);
    glds16(Bw + (long)(j0+sr)*K    + t*32 + sk, bB + 8*T);
    glds16(Bw + (long)(j0+64+sr)*K + t*32 + sk, bB + 2048 + 8*T);
  };
  STAGE(0, lA[0], lB[0]);
  STAGE(1, lA[1], lB[1]);
  int cur = 0, sb = 2;
  for (int t=0;t<16;t++){
    if (t<15){
      if (MODE==0) asm volatile("s_waitcnt vmcnt(4)" ::: "memory");
      else         asm volatile("s_waitcnt vmcnt(3)" ::: "memory");
    } else {
      asm volatile("s_waitcnt vmcnt(0)" ::: "memory");
    }
    __builtin_amdgcn_s_barrier();
    asm volatile("" ::: "memory");
    if (t<14) STAGE(t+2, lA[sb], lB[sb]);
    const u16* cA = lA[cur];
    const u16* cB = lB[cur];
    bf16x8 af[4], bfr[NF];
    #pragma unroll
    for (int mf=0;mf<4;mf++) af[mf]  = *reinterpret_cast<const bf16x8*>(cA + (wr+16*mf+cl)*32 + 8*g);
    #pragma unroll
    for (int nf=0;nf<NF;nf++) bfr[nf] = *reinterpret_cast<const bf16x8*>(cB + (wc+16*nf+cl)*32 + 8*g);
    __builtin_amdgcn_s_setprio(1);
    #pragma unroll
    for (int mf=0;mf<4;mf++)
      #pragma unroll
      for (int nf=0;nf<NF;nf++)
        acc[mf][nf] = __builtin_amdgcn_mfma_f32_16x16x32_bf16(af[mf], bfr[nf], acc[mf][nf], 0,0,0);
    __builtin_amdgcn_s_setprio(0);
    cur = (cur==2)?0:cur+1;
    sb  = (sb==2)?0:sb+1;
  }

  #pragma unroll
  for (int mf=0;mf<4;mf++){
    #pragma unroll
    for (int nf=0;nf<NF;nf++){
      const int col = j0 + wc + 16*nf + cl;
      const float bb = bias[col];
      const int row0 = i0 + wr + 16*mf + 4*g;
      if (MODE==0){
        const int part = col>>9, h=(col>>6)&7, dd=col&63;
        const int b = row0>>10, n0 = row0&1023, bh = b*8+h;
        if (part==2){
          // V^T sigma-permuted within 32-token blocks
          const int a32 = n0 & ~31, G = (n0>>2)&7;
          const int stb = ((G&3)<<3) | ((G>>2)<<2);
          ushort4 pk = make_ushort4(f2bf(acc[mf][nf][0]+bb), f2bf(acc[mf][nf][1]+bb),
                                    f2bf(acc[mf][nf][2]+bb), f2bf(acc[mf][nf][3]+bb));
          *reinterpret_cast<ushort4*>(vo + ((long)bh*64+dd)*1024 + a32 + stb) = pk;
        } else {
          #pragma unroll
          for (int e=0;e<4;e++){
            float v = acc[mf][nf][e] + bb;
            if (part==0) qo[((long)bh*1024+n0+e)*64+dd] = f2bf(v*QSC);
            else         ko[((long)bh*1024+n0+e)*64+dd] = f2bf(v);
          }
        }
      } else {
        #pragma unroll
        for (int e=0;e<4;e++)
          co[(long)(row0+e)*512 + col] = acc[mf][nf][e] + bb;
      }
    }
  }
}

// ---------------- fused window attention, v11 ------------------------------
// qconv FUSED via cooperative LDS-staged conv (18KB scratch reuses K/V bufs
// before first stage). Pair-wise tiles (8 barriers), quad-buffer K/V,
// packed-u64 rel, no-max softmax, 32 q-rows/wave.
__global__ __launch_bounds__(256,2) void k_attn(
  const u16* __restrict__ Qp, const u16* __restrict__ Kb, const u16* __restrict__ VT,
  const u64* __restrict__ relT2, const float* __restrict__ pw, u16* __restrict__ Ao)
{
  __shared__ __align__(16) u16 kls[4][4096];
  __shared__ __align__(16) u16 vls[4][4096];
  const int bid = blockIdx.x;
  const int xcd = bid&7, slot = bid>>3;
  const int bh = xcd*8 + (slot>>3), rb = slot&7;  // all 8 rowblocks of a bh on one XCD
  const int b = bh>>3, h = bh&7;
  const int T = threadIdx.x, w=T>>6, lane=T&63, g=lane>>4, cl=lane&15;
  const int rowbase = rb*128 + w*32;
  const int qr0 = rowbase + cl, qr1 = rowbase + 16 + cl;
  const u16* Qbh = Qp + (long)bh*65536;
  const u16* Kbh = Kb + (long)bh*65536;
  const u16* Vbh = VT + (long)bh*65536;

  bf16x8 qf[2][2];
  // ---- cooperative staged 15-tap conv: Q' fragments from LDS ----
  {
    const int rowstart = rb*128 - 8;
    u16* qs = &kls[0][0];                 // 144 rows x 64 u16 = 18KB scratch
    #pragma unroll
    for (int s=0;s<5;s++){
      int idx = s*256 + T;
      if (idx < 1152){
        int row = idx>>3, u = idx&7;
        int gr = rowstart + row; gr = gr < 0 ? 0 : (gr > 1023 ? 1023 : gr);
        glds16(Qbh + gr*64 + ((u ^ (row&7))<<3), qs + idx*8);
      }
    }
    asm volatile("s_waitcnt vmcnt(0)" ::: "memory");
    __builtin_amdgcn_s_barrier();
    asm volatile("" ::: "memory");
    float wgt[15];
    #pragma unroll
    for (int t=0;t<15;t++) wgt[t] = pw[h*15+t];
    #pragma unroll
    for (int G=0;G<2;G++){
      const int r = rowbase + 16*G + cl;
      const int lr = r - rowstart;        // 8..135 local center row
      #pragma unroll
      for (int s2=0;s2<2;s2++){
        const int ub = 4*s2 + g;          // 16B unit index within row
        float a[8];
        {
          uint4 cv = *reinterpret_cast<const uint4*>(qs + lr*64 + ((ub ^ (lr&7))<<3));
          a[0]=bf2f((u16)cv.x); a[1]=bf2f((u16)(cv.x>>16));
          a[2]=bf2f((u16)cv.y); a[3]=bf2f((u16)(cv.y>>16));
          a[4]=bf2f((u16)cv.z); a[5]=bf2f((u16)(cv.z>>16));
          a[6]=bf2f((u16)cv.w); a[7]=bf2f((u16)(cv.w>>16));
        }
        #pragma unroll
        for (int t=0;t<15;t++){
          int nn = r - 7 + t;
          if (nn >= 0 && nn < 1024){
            int lrow = lr - 7 + t;
            uint4 v = *reinterpret_cast<const uint4*>(qs + lrow*64 + ((ub ^ (lrow&7))<<3));
            acc8(a, v, wgt[t]);
          }
        }
        bf16x8 qq;
        #pragma unroll
        for (int j=0;j<8;j++) qq[j] = (__bf16)a[j];
        qf[G][s2] = qq;
      }
    }
    __builtin_amdgcn_s_barrier();         // all waves done with q scratch
    asm volatile("" ::: "memory");
  }

  const int rt[2] = { (qr0>>5)*63 + (qr0&31) + 1984,
                      (qr1>>5)*63 + (qr1&31) + 1984 };
  const u64* relTh = relT2 + h*3969;
  float lsum[2] = {0.f, 0.f};
  f32x4 oacc[2][4];
  #pragma unroll
  for (int G=0;G<2;G++)
    #pragma unroll
    for (int c=0;c<4;c++) oacc[G][c] = (f32x4){0.f,0.f,0.f,0.f};

  auto STAGE = [&](int m0, int bi){
    #pragma unroll
    for (int s=0;s<2;s++){
      int idx = s*256 + T, row = idx>>3, u = idx&7, sw = (u ^ (row&7))<<3;
      glds16(Kbh + (m0+row)*64 + sw,         kls[bi] + idx*8);
      glds16(Vbh + (long)row*1024 + m0 + sw, vls[bi] + idx*8);
    }
  };
  auto QK = [&](const char* kb, f32x4 (&sacc)[2][4]){
    #pragma unroll
    for (int G=0;G<2;G++)
      #pragma unroll
      for (int c=0;c<4;c++) sacc[G][c] = (f32x4){0.f,0.f,0.f,0.f};
    #pragma unroll
    for (int c=0;c<4;c++){
      const int r = 16*c + cl, rs = r&7;
      const char* kr = kb + r*128;
      bf16x8 kf0 = *reinterpret_cast<const bf16x8*>(kr + ((g    ^rs)<<4));
      bf16x8 kf1 = *reinterpret_cast<const bf16x8*>(kr + (((4+g)^rs)<<4));
      #pragma unroll
      for (int G=0;G<2;G++){
        sacc[G][c] = __builtin_amdgcn_mfma_f32_16x16x32_bf16(kf0, qf[G][0], sacc[G][c],0,0,0);
        sacc[G][c] = __builtin_amdgcn_mfma_f32_16x16x32_bf16(kf1, qf[G][1], sacc[G][c],0,0,0);
      }
    }
  };
  auto RELLOAD = [&](int t, u64 (&rx)[2][4]){
    #pragma unroll
    for (int G=0;G<2;G++)
      #pragma unroll
      for (int c=0;c<4;c++){
        const int kk = (t<<6) + 16*c + 4*g;
        rx[G][c] = relTh[rt[G] - ((kk>>5)*63 + (kk&31))];
      }
  };
  auto SMPV = [&](const char* vb, f32x4 (&sacc)[2][4], u64 (&rx)[2][4]){
    float p[2][4][4];
    #pragma unroll
    for (int G=0;G<2;G++)
      #pragma unroll
      for (int c=0;c<4;c++){
        const u32 lo = (u32)rx[G][c], hi = (u32)(rx[G][c]>>32);
        const float b0 = __builtin_bit_cast(float, hi & 0xffff0000u);
        const float b1 = __builtin_bit_cast(float, hi << 16);
        const float b2 = __builtin_bit_cast(float, lo & 0xffff0000u);
        const float b3 = __builtin_bit_cast(float, lo << 16);
        p[G][c][0] = __builtin_amdgcn_exp2f(sacc[G][c][0] + b0);
        p[G][c][1] = __builtin_amdgcn_exp2f(sacc[G][c][1] + b1);
        p[G][c][2] = __builtin_amdgcn_exp2f(sacc[G][c][2] + b2);
        p[G][c][3] = __builtin_amdgcn_exp2f(sacc[G][c][3] + b3);
      }
    #pragma unroll
    for (int G=0;G<2;G++)
      #pragma unroll
      for (int c=0;c<4;c++) lsum[G] += (p[G][c][0]+p[G][c][1]) + (p[G][c][2]+p[G][c][3]);
    bf16x8 pa[2][2];
    #pragma unroll
    for (int G=0;G<2;G++)
      #pragma unroll
      for (int e=0;e<4;e++){
        pa[G][0][e]   = (__bf16)p[G][0][e];  pa[G][0][4+e] = (__bf16)p[G][1][e];
        pa[G][1][e]   = (__bf16)p[G][2][e];  pa[G][1][4+e] = (__bf16)p[G][3][e];
      }
    #pragma unroll
    for (int ks=0;ks<2;ks++)
      #pragma unroll
      for (int c2=0;c2<4;c2++){
        const int dd = 16*c2 + cl, dsw = dd&7;
        bf16x8 vf = *reinterpret_cast<const bf16x8*>(vb + dd*128 + (((4*ks+g)^dsw)<<4));
        #pragma unroll
        for (int G=0;G<2;G++)
          oacc[G][c2] = __builtin_amdgcn_mfma_f32_16x16x32_bf16(pa[G][ks], vf, oacc[G][c2],0,0,0);
      }
  };

  f32x4 saccA[2][4], saccB[2][4];
  u64 rxA[2][4], rxB[2][4];

  // prologue: stage pair 0 (tiles 0,1 -> buffers 0,1)
  STAGE(0,0); STAGE(64,1);
  asm volatile("s_waitcnt vmcnt(0)" ::: "memory");
  __builtin_amdgcn_s_barrier();
  asm volatile("" ::: "memory");

  for (int p=0;p<8;p++){
    const int t0 = 2*p, t1 = t0+1;
    // stage pair p+1 into the other buffer half (read-done since barrier p-1)
    if (p<7){ STAGE((t0+2)<<6, (t0+2)&3); STAGE((t1+2)<<6, (t1+2)&3); }
    asm volatile("" ::: "memory");       // keep rel loads after stage glds
    RELLOAD(t0, rxA);
    RELLOAD(t1, rxB);
    __builtin_amdgcn_s_setprio(1);
    QK((const char*)kls[t0&3], saccA);
    QK((const char*)kls[t1&3], saccB);   // independent of SMPV(t0) -> interleave
    SMPV((const char*)vls[t0&3], saccA, rxA);
    SMPV((const char*)vls[t1&3], saccB, rxB);
    __builtin_amdgcn_s_setprio(0);
    if (p<7){
      asm volatile("s_waitcnt vmcnt(0)" ::: "memory");
      __builtin_amdgcn_s_barrier();
      asm volatile("" ::: "memory");
    }
  }

  #pragma unroll
  for (int G=0;G<2;G++){
    lsum[G] += __shfl_xor(lsum[G], 16, 64);
    lsum[G] += __shfl_xor(lsum[G], 32, 64);
  }
  #pragma unroll
  for (int G=0;G<2;G++)
    #pragma unroll
    for (int e=0;e<4;e++){
      float inv = 1.0f/__shfl(lsum[G], 4*g+e, 64);
      const long orow = (long)b*1024 + rowbase + 16*G + 4*g + e;
      #pragma unroll
      for (int c2=0;c2<4;c2++)
        Ao[orow*512 + h*64 + 16*c2 + cl] = f2bf(oacc[G][c2][e]*inv);
    }
}

extern "C" void kernel_launch(void* const* d_in, const int* in_sizes, int n_in,
                              void* d_out, int out_size, void* d_ws, size_t ws_size,
                              hipStream_t stream)
{
  const float* x         = (const float*)d_in[0];
  const float* w_qkv     = (const float*)d_in[1];
  const float* b_qkv     = (const float*)d_in[2];
  const float* w_proj    = (const float*)d_in[3];
  const float* b_proj    = (const float*)d_in[4];
  const float* rel_table = (const float*)d_in[5];
  const float* pe_w      = (const float*)d_in[6];
  (void)in_sizes; (void)n_in; (void)out_size; (void)ws_size;

  u16* ws    = (u16*)d_ws;
  u16* x_bf  = ws;                  // 8192*512
  u16* wq_bf = x_bf  + 4194304;     // 1536*512
  u16* wp_bf = wq_bf + 786432;      // 512*512
  u16* q_bf  = wp_bf + 262144;      // [B,H,N,64] pre-scaled by 0.125*log2e
  u16* k_bf  = q_bf  + 4194304;     // [B,H,N,64]
  u16* vt_bf = k_bf  + 4194304;     // [B,H,64,N] sigma-permuted tokens
  u16* ao_bf = vt_bf + 4194304;     // attention out [B,N,C]
  u64* relT2 = (u64*)(ao_bf + 4194304);  // [H][3969] packed u64 (8B aligned)

  k_cvtall<<<5245,256,0,stream>>>(x, w_qkv, w_proj, rel_table, x_bf, wq_bf, wp_bf, relT2);
  k_gemm<0><<<dim3(12,64),256,0,stream>>>(x_bf, wq_bf, b_qkv, q_bf, k_bf, vt_bf, nullptr);
  k_attn<<<512,256,0,stream>>>(q_bf, k_bf, vt_bf, relT2, pe_w, ao_bf);
  k_gemm<1><<<dim3(4,128),256,0,stream>>>(ao_bf, wp_bf, b_proj, nullptr, nullptr, nullptr, (float*)d_out);
}

// Round 12
// 75.996 us; speedup vs baseline: 1.1455x; 1.0304x over previous
//
#include <hip/hip_runtime.h>

typedef __bf16 bf16x8 __attribute__((ext_vector_type(8)));
typedef float f32x4 __attribute__((ext_vector_type(4)));
typedef unsigned short u16;
typedef unsigned int u32;
typedef unsigned long long u64;

__device__ __forceinline__ float bf2f(u16 x){ u32 u = ((u32)x)<<16; return __builtin_bit_cast(float,u); }
__device__ __forceinline__ u16 f2bf(float f){ u32 u = __builtin_bit_cast(u32,f); u = (u + 0x7fffu + ((u>>16)&1u)) >> 16; return (u16)u; }

__device__ __forceinline__ void glds16(const u16* g, u16* l){
  __builtin_amdgcn_global_load_lds((const __attribute__((address_space(1))) u32*)g,
                                   (__attribute__((address_space(3))) u32*)l, 16, 0, 0);
}

static constexpr float L2E = 1.4426950408889634f;
static constexpr float QSC = 0.125f * 1.4426950408889634f;  // SCALE * log2(e)

// --- merged f32->bf16 converts (x, w_qkv, w_proj) + packed rel table -------
// relT2[h][i] = u64 of 4 bf16 {rel[i-3],rel[i-2],rel[i-1],rel[i]} * log2(e)
__global__ void k_cvtall(const float* __restrict__ x, const float* __restrict__ wq,
                         const float* __restrict__ wp, const float* __restrict__ rt,
                         u16* __restrict__ xo, u16* __restrict__ wqo,
                         u16* __restrict__ wpo, u64* __restrict__ rel2){
  int bid = blockIdx.x;
  if (bid < 5120){
    int i = bid*256 + threadIdx.x;       // float4 index over 1310720 total
    const float* s; u16* d; int base;
    if (i < 1048576){ s=x; d=xo; base=0; }
    else if (i < 1245184){ s=wq; d=wqo; base=1048576; }
    else { s=wp; d=wpo; base=1245184; }
    int j = i - base;
    float4 v = reinterpret_cast<const float4*>(s)[j];
    reinterpret_cast<ushort4*>(d)[j] = make_ushort4(f2bf(v.x),f2bf(v.y),f2bf(v.z),f2bf(v.w));
  } else {
    int i = (bid-5120)*256 + threadIdx.x;
    if (i < 31752){
      int h = i / 3969, i2 = i - h*3969;
      u64 v = 0;
      #pragma unroll
      for (int j=0;j<4;j++){
        int idx = i2-3+j;
        u16 bb = 0;
        if (idx >= 0) bb = f2bf(rt[idx*8+h]*L2E);
        v |= (u64)bb << (16*j);
      }
      rel2[i] = v;
    }
  }
}

__device__ __forceinline__ void acc8(float* acc, uint4 v, float w){
  acc[0]=fmaf(w, bf2f((u16)(v.x)),     acc[0]); acc[1]=fmaf(w, bf2f((u16)(v.x>>16)), acc[1]);
  acc[2]=fmaf(w, bf2f((u16)(v.y)),     acc[2]); acc[3]=fmaf(w, bf2f((u16)(v.y>>16)), acc[3]);
  acc[4]=fmaf(w, bf2f((u16)(v.z)),     acc[4]); acc[5]=fmaf(w, bf2f((u16)(v.z>>16)), acc[5]);
  acc[6]=fmaf(w, bf2f((u16)(v.w)),     acc[6]); acc[7]=fmaf(w, bf2f((u16)(v.w>>16)), acc[7]);
}

// ---------------- bf16 MFMA GEMM, C = A * Bw^T + bias ----------------------
// MODE 0: 128x128 tile, qkv scatter. MODE 1: 64x128 tile (2 blocks/CU), f32.
// Triple-buffered LDS, single barrier/k-step, counted vmcnt, XCD swizzle.
template<int MODE>
__global__ __launch_bounds__(256) void k_gemm(
  const u16* __restrict__ A, const u16* __restrict__ Bw, const float* __restrict__ bias,
  u16* __restrict__ qo, u16* __restrict__ ko, u16* __restrict__ vo, float* __restrict__ co)
{
  constexpr int K = 512;
  constexpr int BM = (MODE==0) ? 128 : 64;
  constexpr int NX = (MODE==0) ? 12 : 4;
  constexpr int CPX = NX*(8192/BM)/8;
  constexpr int NF = (MODE==0) ? 4 : 2;
  __shared__ __align__(16) u16 lA[3][BM*32];
  __shared__ __align__(16) u16 lB[3][4096];
  const int lin = blockIdx.y*NX + blockIdx.x;
  const int swz = (lin&7)*CPX + (lin>>3);
  const int i0 = (swz/NX)*BM, j0 = (swz%NX)*128;
  const int T = threadIdx.x;
  const int w = T>>6, lane = T&63, g = lane>>4, cl = lane&15;
  const int wr = (MODE==0) ? (w>>1)*64 : 0;
  const int wc = (MODE==0) ? (w&1)*64 : w*32;
  const int sr = T>>2, sk = 8*(T&3);
  f32x4 acc[4][NF];
  #pragma unroll
  for (int a=0;a<4;a++)
    #pragma unroll
    for (int b=0;b<NF;b++) acc[a][b] = (f32x4){0.f,0.f,0.f,0.f};

  auto STAGE = [&](int t, u16* bA, u16* bB){
    glds16(A  + (long)(i0+sr)*K    + t*32 + sk, bA + 8*T);
    if (MODE==0) glds16(A + (long)(i0+64+sr)*K + t*32 + sk, bA + 2048 + 8*T);
    glds16(Bw + (long)(j0+sr)*K    + t*32 + sk, bB + 8*T);
    glds16(Bw + (long)(j0+64+sr)*K + t*32 + sk, bB + 2048 + 8*T);
  };
  STAGE(0, lA[0], lB[0]);
  STAGE(1, lA[1], lB[1]);
  int cur = 0, sb = 2;
  for (int t=0;t<16;t++){
    if (t<15){
      if (MODE==0) asm volatile("s_waitcnt vmcnt(4)" ::: "memory");
      else         asm volatile("s_waitcnt vmcnt(3)" ::: "memory");
    } else {
      asm volatile("s_waitcnt vmcnt(0)" ::: "memory");
    }
    __builtin_amdgcn_s_barrier();
    asm volatile("" ::: "memory");
    if (t<14) STAGE(t+2, lA[sb], lB[sb]);
    const u16* cA = lA[cur];
    const u16* cB = lB[cur];
    bf16x8 af[4], bfr[NF];
    #pragma unroll
    for (int mf=0;mf<4;mf++) af[mf]  = *reinterpret_cast<const bf16x8*>(cA + (wr+16*mf+cl)*32 + 8*g);
    #pragma unroll
    for (int nf=0;nf<NF;nf++) bfr[nf] = *reinterpret_cast<const bf16x8*>(cB + (wc+16*nf+cl)*32 + 8*g);
    __builtin_amdgcn_s_setprio(1);
    #pragma unroll
    for (int mf=0;mf<4;mf++)
      #pragma unroll
      for (int nf=0;nf<NF;nf++)
        acc[mf][nf] = __builtin_amdgcn_mfma_f32_16x16x32_bf16(af[mf], bfr[nf], acc[mf][nf], 0,0,0);
    __builtin_amdgcn_s_setprio(0);
    cur = (cur==2)?0:cur+1;
    sb  = (sb==2)?0:sb+1;
  }

  #pragma unroll
  for (int mf=0;mf<4;mf++){
    #pragma unroll
    for (int nf=0;nf<NF;nf++){
      const int col = j0 + wc + 16*nf + cl;
      const float bb = bias[col];
      const int row0 = i0 + wr + 16*mf + 4*g;
      if (MODE==0){
        const int part = col>>9, h=(col>>6)&7, dd=col&63;
        const int b = row0>>10, n0 = row0&1023, bh = b*8+h;
        if (part==2){
          // V^T sigma-permuted within 32-token blocks
          const int a32 = n0 & ~31, G = (n0>>2)&7;
          const int stb = ((G&3)<<3) | ((G>>2)<<2);
          ushort4 pk = make_ushort4(f2bf(acc[mf][nf][0]+bb), f2bf(acc[mf][nf][1]+bb),
                                    f2bf(acc[mf][nf][2]+bb), f2bf(acc[mf][nf][3]+bb));
          *reinterpret_cast<ushort4*>(vo + ((long)bh*64+dd)*1024 + a32 + stb) = pk;
        } else {
          #pragma unroll
          for (int e=0;e<4;e++){
            float v = acc[mf][nf][e] + bb;
            if (part==0) qo[((long)bh*1024+n0+e)*64+dd] = f2bf(v*QSC);
            else         ko[((long)bh*1024+n0+e)*64+dd] = f2bf(v);
          }
        }
      } else {
        #pragma unroll
        for (int e=0;e<4;e++)
          co[(long)(row0+e)*512 + col] = acc[mf][nf][e] + bb;
      }
    }
  }
}

// ---------------- fused window attention, v12 ------------------------------
// 512 threads (8 waves), 16 q-rows/wave: doubles waves/CU 8->16 (grid was the
// occupancy binder). Fused LDS conv, pair-wise tiles, quad-buffer K/V,
// packed-u64 rel, no-max softmax.
__global__ __launch_bounds__(512,4) void k_attn(
  const u16* __restrict__ Qp, const u16* __restrict__ Kb, const u16* __restrict__ VT,
  const u64* __restrict__ relT2, const float* __restrict__ pw, u16* __restrict__ Ao)
{
  __shared__ __align__(16) u16 kls[4][4096];
  __shared__ __align__(16) u16 vls[4][4096];
  const int bid = blockIdx.x;
  const int xcd = bid&7, slot = bid>>3;
  const int bh = xcd*8 + (slot>>3), rb = slot&7;  // all 8 rowblocks of a bh on one XCD
  const int b = bh>>3, h = bh&7;
  const int T = threadIdx.x, w=T>>6, lane=T&63, g=lane>>4, cl=lane&15;
  const int rowbase = rb*128 + w*16;
  const int qr = rowbase + cl;
  const u16* Qbh = Qp + (long)bh*65536;
  const u16* Kbh = Kb + (long)bh*65536;
  const u16* Vbh = VT + (long)bh*65536;

  bf16x8 qf[2];
  // ---- cooperative staged 15-tap conv: Q' fragments from LDS ----
  {
    const int rowstart = rb*128 - 8;
    u16* qs = &kls[0][0];                 // 144 rows x 64 u16 = 18KB scratch
    #pragma unroll
    for (int s=0;s<3;s++){
      int idx = s*512 + T;
      if (idx < 1152){
        int row = idx>>3, u = idx&7;
        int gr = rowstart + row; gr = gr < 0 ? 0 : (gr > 1023 ? 1023 : gr);
        glds16(Qbh + gr*64 + ((u ^ (row&7))<<3), qs + idx*8);
      }
    }
    asm volatile("s_waitcnt vmcnt(0)" ::: "memory");
    __builtin_amdgcn_s_barrier();
    asm volatile("" ::: "memory");
    float wgt[15];
    #pragma unroll
    for (int t=0;t<15;t++) wgt[t] = pw[h*15+t];
    const int lr = qr - rowstart;         // 8..135 local center row
    #pragma unroll
    for (int s2=0;s2<2;s2++){
      const int ub = 4*s2 + g;            // 16B unit index within row
      float a[8];
      {
        uint4 cv = *reinterpret_cast<const uint4*>(qs + lr*64 + ((ub ^ (lr&7))<<3));
        a[0]=bf2f((u16)cv.x); a[1]=bf2f((u16)(cv.x>>16));
        a[2]=bf2f((u16)cv.y); a[3]=bf2f((u16)(cv.y>>16));
        a[4]=bf2f((u16)cv.z); a[5]=bf2f((u16)(cv.z>>16));
        a[6]=bf2f((u16)cv.w); a[7]=bf2f((u16)(cv.w>>16));
      }
      #pragma unroll
      for (int t=0;t<15;t++){
        int nn = qr - 7 + t;
        if (nn >= 0 && nn < 1024){
          int lrow = lr - 7 + t;
          uint4 v = *reinterpret_cast<const uint4*>(qs + lrow*64 + ((lrow&7)<<3 ^ (ub<<3)));
          acc8(a, v, wgt[t]);
        }
      }
      bf16x8 qq;
      #pragma unroll
      for (int j=0;j<8;j++) qq[j] = (__bf16)a[j];
      qf[s2] = qq;
    }
    __builtin_amdgcn_s_barrier();         // all waves done with q scratch
    asm volatile("" ::: "memory");
  }

  const int rt = (qr>>5)*63 + (qr&31) + 1984;
  const u64* relTh = relT2 + h*3969;
  float lsum = 0.f;
  f32x4 oacc[4];
  #pragma unroll
  for (int c=0;c<4;c++) oacc[c] = (f32x4){0.f,0.f,0.f,0.f};

  auto STAGE = [&](int m0, int bi){
    int row = T>>3, u = T&7, sw = (u ^ (row&7))<<3;
    glds16(Kbh + (m0+row)*64 + sw,         kls[bi] + T*8);
    glds16(Vbh + (long)row*1024 + m0 + sw, vls[bi] + T*8);
  };
  auto QK = [&](const char* kb, f32x4 (&sacc)[4]){
    #pragma unroll
    for (int c=0;c<4;c++) sacc[c] = (f32x4){0.f,0.f,0.f,0.f};
    #pragma unroll
    for (int c=0;c<4;c++){
      const int r = 16*c + cl, rs = r&7;
      const char* kr = kb + r*128;
      bf16x8 kf0 = *reinterpret_cast<const bf16x8*>(kr + ((g    ^rs)<<4));
      bf16x8 kf1 = *reinterpret_cast<const bf16x8*>(kr + (((4+g)^rs)<<4));
      sacc[c] = __builtin_amdgcn_mfma_f32_16x16x32_bf16(kf0, qf[0], sacc[c],0,0,0);
      sacc[c] = __builtin_amdgcn_mfma_f32_16x16x32_bf16(kf1, qf[1], sacc[c],0,0,0);
    }
  };
  auto RELLOAD = [&](int t, u64 (&rx)[4]){
    #pragma unroll
    for (int c=0;c<4;c++){
      const int kk = (t<<6) + 16*c + 4*g;
      rx[c] = relTh[rt - ((kk>>5)*63 + (kk&31))];
    }
  };
  auto SMPV = [&](const char* vb, f32x4 (&sacc)[4], u64 (&rx)[4]){
    float p[4][4];
    #pragma unroll
    for (int c=0;c<4;c++){
      const u32 lo = (u32)rx[c], hi = (u32)(rx[c]>>32);
      const float b0 = __builtin_bit_cast(float, hi & 0xffff0000u);
      const float b1 = __builtin_bit_cast(float, hi << 16);
      const float b2 = __builtin_bit_cast(float, lo & 0xffff0000u);
      const float b3 = __builtin_bit_cast(float, lo << 16);
      p[c][0] = __builtin_amdgcn_exp2f(sacc[c][0] + b0);
      p[c][1] = __builtin_amdgcn_exp2f(sacc[c][1] + b1);
      p[c][2] = __builtin_amdgcn_exp2f(sacc[c][2] + b2);
      p[c][3] = __builtin_amdgcn_exp2f(sacc[c][3] + b3);
    }
    #pragma unroll
    for (int c=0;c<4;c++) lsum += (p[c][0]+p[c][1]) + (p[c][2]+p[c][3]);
    bf16x8 pa0, pa1;
    #pragma unroll
    for (int e=0;e<4;e++){
      pa0[e]   = (__bf16)p[0][e];  pa0[4+e] = (__bf16)p[1][e];
      pa1[e]   = (__bf16)p[2][e];  pa1[4+e] = (__bf16)p[3][e];
    }
    #pragma unroll
    for (int ks=0;ks<2;ks++){
      const bf16x8 pa = ks ? pa1 : pa0;
      #pragma unroll
      for (int c2=0;c2<4;c2++){
        const int dd = 16*c2 + cl, dsw = dd&7;
        bf16x8 vf = *reinterpret_cast<const bf16x8*>(vb + dd*128 + (((4*ks+g)^dsw)<<4));
        oacc[c2] = __builtin_amdgcn_mfma_f32_16x16x32_bf16(pa, vf, oacc[c2],0,0,0);
      }
    }
  };

  f32x4 saccA[4], saccB[4];
  u64 rxA[4], rxB[4];

  // prologue: stage pair 0 (tiles 0,1 -> buffers 0,1)
  STAGE(0,0); STAGE(64,1);
  asm volatile("s_waitcnt vmcnt(0)" ::: "memory");
  __builtin_amdgcn_s_barrier();
  asm volatile("" ::: "memory");

  for (int p=0;p<8;p++){
    const int t0 = 2*p, t1 = t0+1;
    // stage pair p+1 into the other buffer half (read-done since barrier p-1)
    if (p<7){ STAGE((t0+2)<<6, (t0+2)&3); STAGE((t1+2)<<6, (t1+2)&3); }
    asm volatile("" ::: "memory");       // keep rel loads after stage glds
    RELLOAD(t0, rxA);
    RELLOAD(t1, rxB);
    __builtin_amdgcn_s_setprio(1);
    QK((const char*)kls[t0&3], saccA);
    QK((const char*)kls[t1&3], saccB);   // independent of SMPV(t0) -> interleave
    SMPV((const char*)vls[t0&3], saccA, rxA);
    SMPV((const char*)vls[t1&3], saccB, rxB);
    __builtin_amdgcn_s_setprio(0);
    if (p<7){
      asm volatile("s_waitcnt vmcnt(0)" ::: "memory");
      __builtin_amdgcn_s_barrier();
      asm volatile("" ::: "memory");
    }
  }

  lsum += __shfl_xor(lsum, 16, 64);
  lsum += __shfl_xor(lsum, 32, 64);
  #pragma unroll
  for (int e=0;e<4;e++){
    float inv = 1.0f/__shfl(lsum, 4*g+e, 64);
    const long orow = (long)b*1024 + rowbase + 4*g + e;
    #pragma unroll
    for (int c2=0;c2<4;c2++)
      Ao[orow*512 + h*64 + 16*c2 + cl] = f2bf(oacc[c2][e]*inv);
  }
}

extern "C" void kernel_launch(void* const* d_in, const int* in_sizes, int n_in,
                              void* d_out, int out_size, void* d_ws, size_t ws_size,
                              hipStream_t stream)
{
  const float* x         = (const float*)d_in[0];
  const float* w_qkv     = (const float*)d_in[1];
  const float* b_qkv     = (const float*)d_in[2];
  const float* w_proj    = (const float*)d_in[3];
  const float* b_proj    = (const float*)d_in[4];
  const float* rel_table = (const float*)d_in[5];
  const float* pe_w      = (const float*)d_in[6];
  (void)in_sizes; (void)n_in; (void)out_size; (void)ws_size;

  u16* ws    = (u16*)d_ws;
  u16* x_bf  = ws;                  // 8192*512
  u16* wq_bf = x_bf  + 4194304;     // 1536*512
  u16* wp_bf = wq_bf + 786432;      // 512*512
  u16* q_bf  = wp_bf + 262144;      // [B,H,N,64] pre-scaled by 0.125*log2e
  u16* k_bf  = q_bf  + 4194304;     // [B,H,N,64]
  u16* vt_bf = k_bf  + 4194304;     // [B,H,64,N] sigma-permuted tokens
  u16* ao_bf = vt_bf + 4194304;     // attention out [B,N,C]
  u64* relT2 = (u64*)(ao_bf + 4194304);  // [H][3969] packed u64 (8B aligned)

  k_cvtall<<<5245,256,0,stream>>>(x, w_qkv, w_proj, rel_table, x_bf, wq_bf, wp_bf, relT2);
  k_gemm<0><<<dim3(12,64),256,0,stream>>>(x_bf, wq_bf, b_qkv, q_bf, k_bf, vt_bf, nullptr);
  k_attn<<<512,512,0,stream>>>(q_bf, k_bf, vt_bf, relT2, pe_w, ao_bf);
  k_gemm<1><<<dim3(4,128),256,0,stream>>>(ao_bf, wp_bf, b_proj, nullptr, nullptr, nullptr, (float*)d_out);
}